// Round 6
// baseline (395.498 us; speedup 1.0000x reference)
//
#include <hip/hip_runtime.h>
#include <stdint.h>

#define FH 64
#define FW 64
#define CIN 1536
#define C3C 512
#define C4C 1024
#define COUT 512
#define BATCH 16
#define NPIX 4096
#define NBOX 10
#define MPAD 256   // 10 boxes * 25 bins = 250, padded
#define KT128 12   // CIN/128 K-tiles

// mega_pre flat-grid segments
#define NB_FU 12288              // build_fusedT: 12*64*16
#define NB_P  4000               // build_P: 160*25
#define NB_W  768                // conv_w: 196608/256
#define NB_BN 2                  // prep_bn: 512/256
#define NB_CP 3                  // boxes->out copy: 640/256 rounded up
#define NB_TOT (NB_FU + NB_P + NB_W + NB_BN + NB_CP)

typedef float v4f __attribute__((ext_vector_type(4)));
typedef long  v2l __attribute__((ext_vector_type(2)));

#define GLOAD_LDS16(g, l) __builtin_amdgcn_global_load_lds( \
    (const __attribute__((address_space(1))) void*)(g),     \
    (__attribute__((address_space(3))) void*)(l), 16, 0, 0)

#define BARRIER() asm volatile("s_barrier" ::: "memory")

// pack 4 floats -> 4 fp8 e4m3 bytes in one u32 (byte k = f[k])
__device__ __forceinline__ uint32_t pack4_fp8(float a, float b, float c, float d) {
    int lo = __builtin_amdgcn_cvt_pk_fp8_f32(a, b, 0, false);
    int v  = __builtin_amdgcn_cvt_pk_fp8_f32(c, d, lo, true);
    return (uint32_t)v;
}
__device__ __forceinline__ unsigned char f32_to_fp8(float a) {
    return (unsigned char)(__builtin_amdgcn_cvt_pk_fp8_f32(a, a, 0, false) & 0xff);
}

// K-permutation within each 128-byte K-block of w8/fusedT:
// logical k7 stored at byte quad*32 + s*8 + b  (quad=(k7>>3)&3, s=k7>>5, b=k7&7).
// Makes each lane's MFMA operand pair {s,s+1} 16 contiguous bytes -> ds_read_b128.
// Applied identically to BOTH operands, so sum_k A[m][k]B[n][k] is preserved.

// ---------------- mega_pre: all input-only stages in ONE dispatch ----------
// Segments (flat blockIdx.x): [build_fusedT | build_P | conv_w | prep_bn | copy]
// All segments are mutually independent (read only harness inputs).
// Rationale: ~150 us of the 395 us total was inter-dispatch overhead
// (8 stream ops x ~20 us); this collapses 5 ops into 1.
__global__ __launch_bounds__(256) void mega_pre(
        const float* __restrict__ c3, const float* __restrict__ c4,
        const float* __restrict__ boxes,
        const float* __restrict__ w_conv, const float* __restrict__ b_conv,
        const float* __restrict__ bng, const float* __restrict__ bnb,
        const float* __restrict__ bnm, const float* __restrict__ bnv,
        unsigned char* __restrict__ fusedT, unsigned char* __restrict__ P,
        unsigned char* __restrict__ w8,
        float* __restrict__ scale, float* __restrict__ shift,
        float* __restrict__ out) {
    __shared__ uint32_t lds[64 * 36];
    const int bid = blockIdx.x;
    const int t   = threadIdx.x;

    if (bid < NB_FU) {
        // ---- build fusedT[b][pix][c] fp8 (K-major, k-permuted) ----
        // c4 path: float2 loads + cross-lane shuffles (was VMEM-issue-bound).
        // LDS chunk XOR-swizzled by (px>>1)&7 (write was 8-way conflicted).
        int ct = bid % 12;            // 0..11; <4 -> c3, else c4
        int rest = bid / 12;
        int y  = rest & 63;
        int b  = rest >> 6;
        int pg = t & 15;              // pixel quad: px 4pg..4pg+3
        int cq = t >> 4;              // 0..15; cquad = cq + 16r

        #pragma unroll
        for (int r = 0; r < 2; ++r) {
            int cquad = cq + 16 * r;
            float vv[4][4];           // [channel][pixel]
            if (ct < 4) {
                int ch = ct * 128 + 4 * cquad;
                const float* src = c3 + (((size_t)(b * C3C + ch) * FH + y) * FW) + 4 * pg;
                #pragma unroll
                for (int k = 0; k < 4; ++k) {
                    float4 f = *(const float4*)(src + (size_t)k * (FH * FW));
                    vv[k][0] = f.x; vv[k][1] = f.y; vv[k][2] = f.z; vv[k][3] = f.w;
                }
            } else {
                int ch = ct * 128 - 512 + 4 * cquad;
                int jy = y >> 1;
                int jyB = min(max(jy + ((y & 1) ? 1 : -1), 0), 31);
                const float* base = c4 + (size_t)(b * C4C + ch) * 1024;
                #pragma unroll
                for (int k = 0; k < 4; ++k) {
                    const float* pc = base + (size_t)k * 1024;
                    float2 f0 = *(const float2*)(pc + jy * 32 + 2 * pg);
                    float2 f1 = *(const float2*)(pc + jyB * 32 + 2 * pg);
                    float rbA = 0.75f * f0.x + 0.25f * f1.x;   // rb[2pg]
                    float rbB = 0.75f * f0.y + 0.25f * f1.y;   // rb[2pg+1]
                    float rbm = __shfl_up(rbB, 1, 16);          // rb[2pg-1]
                    float rbp = __shfl_down(rbA, 1, 16);        // rb[2pg+2]
                    if (pg == 0)  rbm = rbA;                    // km clamp
                    if (pg == 15) rbp = rbB;                    // kp clamp
                    vv[k][0] = 0.75f * rbA + 0.25f * rbm;
                    vv[k][1] = 0.75f * rbA + 0.25f * rbB;
                    vv[k][2] = 0.75f * rbB + 0.25f * rbA;
                    vv[k][3] = 0.75f * rbB + 0.25f * rbp;
                }
            }
            #pragma unroll
            for (int i = 0; i < 4; ++i) {
                int px = 4 * pg + i;
                lds[px * 36 + 4 * ((cquad >> 2) ^ ((px >> 1) & 7)) + (cquad & 3)] =
                    pack4_fp8(vv[0][i], vv[1][i], vv[2][i], vv[3][i]);
            }
        }
        __syncthreads();
        // write: 64 px x 128 B; thread covers one 16-B logical chunk as 2x8B
        int g = t & 7;                 // 16-channel group
        #pragma unroll
        for (int rr2 = 0; rr2 < 2; ++rr2) {
            int px = (t >> 3) + 32 * rr2;
            uint4 w = *(const uint4*)(&lds[px * 36 + 4 * (g ^ ((px >> 1) & 7))]);
            unsigned char* dst = fusedT + ((size_t)b * NPIX + y * FW + px) * CIN + ct * 128;
            int pos0 = ((2 * g) & 3) * 32 + (g >> 1) * 8;
            int pos1 = ((2 * g + 1) & 3) * 32 + (g >> 1) * 8;
            *(uint2*)(dst + pos0) = make_uint2(w.x, w.y);
            *(uint2*)(dst + pos1) = make_uint2(w.z, w.w);
        }
    } else if (bid < NB_FU + NB_P) {
        // ---- build pooling matrix P[b][m][pix] fp8 (x64) ----
        int id  = bid - NB_FU;
        int br  = id % 160;
        int m25 = id / 160;
        int b   = br / NBOX;
        int m   = (br % NBOX) * 25 + m25;
        int p   = m25 / 5, q = m25 % 5;
        int y   = t >> 2;
        int x0  = (t & 3) * 16;
        const float* bx = boxes + (size_t)br * 4;
        int x1 = min(max((int)floorf(bx[0] * 0.125f), 0), 63);
        int y1 = min(max((int)floorf(bx[1] * 0.125f), 0), 63);
        int x2 = min(max((int)ceilf (bx[2] * 0.125f), 0), 63);
        int y2 = min(max((int)ceilf (bx[3] * 0.125f), 0), 63);
        if (x2 <= x1) x2 = min(x1 + 1, 64);
        if (y2 <= y1) y2 = min(y1 + 1, 64);
        int Lx = x2 - x1, Ly = y2 - y1;
        int sx = x1 + (q * Lx) / 5;
        int ex = x1 + ((q + 1) * Lx + 4) / 5;
        int sy = y1 + (p * Ly) / 5;
        int ey = y1 + ((p + 1) * Ly + 4) / 5;
        float wyv  = (y >= sy && y < ey) ? 1.0f / (float)(ey - sy) : 0.0f;
        float pval = 64.0f * wyv / (float)(ex - sx);
        float v[16];
        #pragma unroll
        for (int i = 0; i < 16; ++i) {
            int xi = x0 + i;
            v[i] = (xi >= sx && xi < ex) ? pval : 0.0f;
        }
        uint4 w;
        w.x = pack4_fp8(v[0],  v[1],  v[2],  v[3]);
        w.y = pack4_fp8(v[4],  v[5],  v[6],  v[7]);
        w.z = pack4_fp8(v[8],  v[9],  v[10], v[11]);
        w.w = pack4_fp8(v[12], v[13], v[14], v[15]);
        *(uint4*)(P + ((size_t)b * MPAD + m) * NPIX + y * FW + x0) = w;
    } else if (bid < NB_FU + NB_P + NB_W) {
        // ---- W f32 -> fp8 (x16), k-permuted layout ----
        int i = (bid - NB_FU - NB_P) * 256 + t;
        if (i < COUT * CIN / 4) {
            float4 f = *(const float4*)(w_conv + i * 4);
            uint32_t v = pack4_fp8(f.x * 16.0f, f.y * 16.0f, f.z * 16.0f, f.w * 16.0f);
            int c0 = (i * 4) % CIN;
            int o  = (i * 4) / CIN;
            int k7 = c0 & 127;
            int pos = ((k7 >> 3) & 3) * 32 + (k7 >> 5) * 8 + (k7 & 7);
            *(uint32_t*)(w8 + (size_t)o * CIN + (c0 & ~127) + pos) = v;
        }
    } else if (bid < NB_FU + NB_P + NB_W + NB_BN) {
        // ---- BN constant folding ----
        int o = (bid - NB_FU - NB_P - NB_W) * 256 + t;
        if (o < COUT) {
            float inv = bng[o] / sqrtf(bnv[o] + 1e-5f);
            scale[o] = inv * 0.0625f;             // /16: W quantized as W*16
            shift[o] = bnb[o] + inv * (b_conv[o] - bnm[o]);
        }
    } else {
        // ---- boxes -> out[0:640] copy (replaces hipMemcpyAsync) ----
        int i = (bid - NB_FU - NB_P - NB_W - NB_BN) * 256 + t;
        if (i < 640) out[i] = boxes[i];
    }
}

// ---------------- fp8 GEMM + BN + ReLU, 256x256 tile, BK=128, 2-phase ------
// k-permuted operands -> each fragment pair is one conflict-free
// ds_read_b128; counted vmcnt, raw s_barrier, setprio around MFMA.
__global__ __launch_bounds__(512, 2) void gemm_bn_relu(
        const unsigned char* __restrict__ w8,
        const unsigned char* __restrict__ fusedT,
        const float* __restrict__ scale, const float* __restrict__ shift,
        unsigned char* __restrict__ attr) {
    __shared__ __align__(16) unsigned char lds_a[2][32768];
    __shared__ __align__(16) unsigned char lds_b[2][32768];
    const int t  = threadIdx.x;
    const int n0 = blockIdx.x * 256;   // pixel tile
    const int o0 = blockIdx.y * 256;   // out-channel tile
    const int b  = blockIdx.z;
    const int wave = t >> 6, lane = t & 63;
    const int wm = wave & 1, wn = wave >> 1;   // 2 x 4 wave grid
    const int quad = lane >> 4, l16 = lane & 15;
    // b128 chunk offsets: chunk c = quad*2+h stored at (c ^ (row&7)); row&7 = l16&7
    const int cp0 = (((quad << 1) ^ (l16 & 7)) << 4);
    const int cp1 = cp0 ^ 16;
    const unsigned char* fb = fusedT + (size_t)b * NPIX * CIN;

    // ---- staging: 512 threads cover one 64row x 128B unit ----
    const int rr = t >> 3;                        // row within unit (0..63)
    const int cg = (t & 7) ^ (rr & 7);            // inverse-swizzled src chunk
    const unsigned char* gA = w8 + (size_t)(o0 + rr) * CIN + cg * 16;
    const unsigned char* gB = fb + (size_t)(n0 + rr) * CIN + cg * 16;

#define SA(u, kt, d) GLOAD_LDS16(gA + (size_t)(u) * (64 * CIN) + (kt) * 128, \
                                 &lds_a[d][(u) * 8192 + t * 16])
#define SB(u, kt, d) GLOAD_LDS16(gB + (size_t)(u) * (64 * CIN) + (kt) * 128, \
                                 &lds_b[d][(u) * 8192 + t * 16])
#define RAV(d, ph, i, cp) (*(const v2l*)(&lds_a[d][((wm * 128 + (ph) * 64 + (i) * 16 + l16) << 7) + (cp)]))
#define RBV(d, j, cp)     (*(const v2l*)(&lds_b[d][((wn * 64 + (j) * 16 + l16) << 7) + (cp)]))

    v4f acc[8][4];   // [ph*4+i][j]
    #pragma unroll
    for (int i = 0; i < 8; ++i)
        #pragma unroll
        for (int j = 0; j < 4; ++j) acc[i][j] = (v4f)0.0f;

    // ---- prologue: tile0 full (8 units) + S1(tile1) (6 units) ----
    SA(0, 0, 0); SA(1, 0, 0); SA(2, 0, 0); SA(3, 0, 0);
    SB(0, 0, 0); SB(1, 0, 0); SB(2, 0, 0); SB(3, 0, 0);
    SA(0, 1, 1); SA(2, 1, 1); SB(0, 1, 1); SB(1, 1, 1); SB(2, 1, 1); SB(3, 1, 1);
    asm volatile("s_waitcnt vmcnt(6)" ::: "memory");
    BARRIER();

    v2l ah0[4], ah1[4], bh0[4], bh1[4];

    for (int kt = 0; kt < KT128; ++kt) {
        const int cur = kt & 1, nxt = cur ^ 1;

        // ---- phase 1: A rows wm*128..+64 x all B ----
        #pragma unroll
        for (int i = 0; i < 4; ++i) { ah0[i] = RAV(cur, 0, i, cp0); ah1[i] = RAV(cur, 0, i, cp1); }
        #pragma unroll
        for (int j = 0; j < 4; ++j) { bh0[j] = RBV(cur, j, cp0); bh1[j] = RBV(cur, j, cp1); }
        if (kt > 0 && kt + 1 < KT128) {
            SA(0, kt + 1, nxt); SA(2, kt + 1, nxt);
            SB(0, kt + 1, nxt); SB(1, kt + 1, nxt);
            SB(2, kt + 1, nxt); SB(3, kt + 1, nxt);
        }
        __builtin_amdgcn_s_setprio(1);
        #pragma unroll
        for (int s = 0; s < 2; ++s)
            #pragma unroll
            for (int i = 0; i < 4; ++i)
                #pragma unroll
                for (int j = 0; j < 4; ++j)
                    acc[i][j] = __builtin_amdgcn_mfma_f32_16x16x32_fp8_fp8(ah0[i][s], bh0[j][s], acc[i][j], 0, 0, 0);
        #pragma unroll
        for (int s = 0; s < 2; ++s)
            #pragma unroll
            for (int i = 0; i < 4; ++i)
                #pragma unroll
                for (int j = 0; j < 4; ++j)
                    acc[i][j] = __builtin_amdgcn_mfma_f32_16x16x32_fp8_fp8(ah1[i][s], bh1[j][s], acc[i][j], 0, 0, 0);
        __builtin_amdgcn_s_setprio(0);
        if (kt + 1 < KT128) { asm volatile("s_waitcnt vmcnt(6)" ::: "memory"); }
        else               { asm volatile("s_waitcnt vmcnt(0)" ::: "memory"); }
        BARRIER();

        // ---- phase 2: A rows wm*128+64..+128 (B frags reused) ----
        #pragma unroll
        for (int i = 0; i < 4; ++i) { ah0[i] = RAV(cur, 1, i, cp0); ah1[i] = RAV(cur, 1, i, cp1); }
        if (kt + 1 < KT128) { SA(1, kt + 1, nxt); SA(3, kt + 1, nxt); }
        __builtin_amdgcn_s_setprio(1);
        #pragma unroll
        for (int s = 0; s < 2; ++s)
            #pragma unroll
            for (int i = 0; i < 4; ++i)
                #pragma unroll
                for (int j = 0; j < 4; ++j)
                    acc[4 + i][j] = __builtin_amdgcn_mfma_f32_16x16x32_fp8_fp8(ah0[i][s], bh0[j][s], acc[4 + i][j], 0, 0, 0);
        #pragma unroll
        for (int s = 0; s < 2; ++s)
            #pragma unroll
            for (int i = 0; i < 4; ++i)
                #pragma unroll
                for (int j = 0; j < 4; ++j)
                    acc[4 + i][j] = __builtin_amdgcn_mfma_f32_16x16x32_fp8_fp8(ah1[i][s], bh1[j][s], acc[4 + i][j], 0, 0, 0);
        __builtin_amdgcn_s_setprio(0);
        if (kt + 1 < KT128) { asm volatile("s_waitcnt vmcnt(2)" ::: "memory"); }
        BARRIER();
    }

    // ---- epilogue: BN + ReLU + fp8 channel-major store ----
    unsigned char* ab = attr + (size_t)b * COUT * NPIX;
    #pragma unroll
    for (int a = 0; a < 8; ++a) {
        int obase = o0 + wm * 128 + (a >> 2) * 64 + (a & 3) * 16 + quad * 4;
        #pragma unroll
        for (int r = 0; r < 4; ++r) {
            int oo = obase + r;
            float sc = scale[oo], sh = shift[oo];
            #pragma unroll
            for (int j = 0; j < 4; ++j) {
                int n = n0 + wn * 64 + j * 16 + l16;
                float v = fmaxf(acc[a][j][r] * sc + sh, 0.0f);
                ab[(size_t)oo * NPIX + n] = f32_to_fp8(v);
            }
        }
    }
#undef SA
#undef SB
#undef RAV
#undef RBV
}

// ---------------- fp8 pool GEMM, full K=4096 in-block, direct out ----------
// K-split removed (was 4 segs + part2 + pool_reduce): 64 K-steps per block,
// epilogue applies the /64 P-scaling and writes out[] directly with the
// reduce kernel's transpose indexing. Deletes 66 MB part2 traffic + 1
// dispatch boundary.
__global__ __launch_bounds__(256) void pool_fused(
        const unsigned char* __restrict__ P,
        const unsigned char* __restrict__ attr,
        float* __restrict__ out) {
    __shared__ __align__(16) unsigned char lds_a[128 * 64];
    __shared__ __align__(16) unsigned char lds_b[128 * 64];
    int t  = threadIdx.x;
    int m0 = blockIdx.x * 128;
    int c0 = blockIdx.y * 128;
    int b  = blockIdx.z;
    int wave = t >> 6, lane = t & 63;
    int wm = wave & 1, wn = wave >> 1;
    int quad = lane >> 4, l16 = lane & 15;
    const unsigned char* Pb = P + (size_t)b * MPAD * NPIX;
    const unsigned char* ab = attr + (size_t)b * COUT * NPIX;

    v4f acc[4][4];
    #pragma unroll
    for (int i = 0; i < 4; ++i)
        #pragma unroll
        for (int j = 0; j < 4; ++j) acc[i][j] = (v4f)0.0f;

    int row = t >> 2;
    int cg  = (t & 3) ^ ((row >> 1) & 3);
    const unsigned char* ga0 = Pb + (size_t)(m0 + row) * NPIX + cg * 16;
    const unsigned char* ga1 = Pb + (size_t)(m0 + row + 64) * NPIX + cg * 16;
    const unsigned char* gb0 = ab + (size_t)(c0 + row) * NPIX + cg * 16;
    const unsigned char* gb1 = ab + (size_t)(c0 + row + 64) * NPIX + cg * 16;
    unsigned char* la0 = lds_a + t * 16;
    unsigned char* la1 = lds_a + 4096 + t * 16;
    unsigned char* lb0 = lds_b + t * 16;
    unsigned char* lb1 = lds_b + 4096 + t * 16;

    int ra[4], rb[4];
    #pragma unroll
    for (int i = 0; i < 4; ++i) { ra[i] = wm * 64 + i * 16 + l16; rb[i] = wn * 64 + i * 16 + l16; }
    int q2 = quad >> 1, q1 = (quad & 1) * 8;

    for (int kt = 0; kt < NPIX / 64; ++kt) {
        __syncthreads();
        GLOAD_LDS16(ga0, la0);
        GLOAD_LDS16(ga1, la1);
        GLOAD_LDS16(gb0, lb0);
        GLOAD_LDS16(gb1, lb1);
        ga0 += 64; ga1 += 64; gb0 += 64; gb1 += 64;
        __syncthreads();

        #pragma unroll
        for (int s = 0; s < 2; ++s) {
            long af[4], bf[4];
            #pragma unroll
            for (int i = 0; i < 4; ++i) {
                int pa = (2 * s + q2) ^ ((ra[i] >> 1) & 3);
                af[i] = *(const long*)(lds_a + ra[i] * 64 + pa * 16 + q1);
                int pb = (2 * s + q2) ^ ((rb[i] >> 1) & 3);
                bf[i] = *(const long*)(lds_b + rb[i] * 64 + pb * 16 + q1);
            }
            #pragma unroll
            for (int i = 0; i < 4; ++i)
                #pragma unroll
                for (int j = 0; j < 4; ++j)
                    acc[i][j] = __builtin_amdgcn_mfma_f32_16x16x32_fp8_fp8(af[i], bf[j], acc[i][j], 0, 0, 0);
        }
    }

    // epilogue: /64 scaling + transpose to out (mrow>=250 is pad, skipped)
    #pragma unroll
    for (int i = 0; i < 4; ++i) {
        #pragma unroll
        for (int r = 0; r < 4; ++r) {
            int mrow = m0 + wm * 64 + i * 16 + quad * 4 + r;
            if (mrow < 250) {
                int box = mrow / 25, bin = mrow - box * 25;
                float* ob = out + 640 + ((size_t)(b * NBOX + box) * COUT) * 25 + bin;
                #pragma unroll
                for (int j = 0; j < 4; ++j) {
                    int c = c0 + wn * 64 + j * 16 + l16;
                    ob[(size_t)c * 25] = acc[i][j][r] * 0.015625f;
                }
            }
        }
    }
}

extern "C" void kernel_launch(void* const* d_in, const int* in_sizes, int n_in,
                              void* d_out, int out_size, void* d_ws, size_t ws_size,
                              hipStream_t stream) {
    const float* c3     = (const float*)d_in[0];
    const float* c4     = (const float*)d_in[1];
    const float* boxes  = (const float*)d_in[2];
    const float* w_conv = (const float*)d_in[3];
    const float* b_conv = (const float*)d_in[4];
    const float* bng    = (const float*)d_in[5];
    const float* bnb    = (const float*)d_in[6];
    const float* bnm    = (const float*)d_in[7];
    const float* bnv    = (const float*)d_in[8];
    float* out = (float*)d_out;

    char* ws = (char*)d_ws;
    // fp8 layout (no aliasing needed):
    unsigned char* fusedT = (unsigned char*)ws;                 // 100663296 B
    unsigned char* P      = (unsigned char*)(ws + 100663296);   //  16777216 B
    unsigned char* w8     = (unsigned char*)(ws + 117440512);   //    786432 B
    float*         scale  = (float*)(ws + 118226944);           //      2048 B
    float*         shift  = (float*)(ws + 118228992);           //      2048 B
    unsigned char* attr   = (unsigned char*)(ws + 118231040);   //  33554432 B

    mega_pre<<<NB_TOT, 256, 0, stream>>>(c3, c4, boxes, w_conv, b_conv,
                                         bng, bnb, bnm, bnv,
                                         fusedT, P, w8, scale, shift, out);
    gemm_bn_relu<<<dim3(16, 2, 16), 512, 0, stream>>>(w8, fusedT, scale, shift, attr);
    pool_fused<<<dim3(2, 4, 16), 256, 0, stream>>>(P, attr, out);
    (void)in_sizes; (void)n_in; (void)out_size; (void)ws_size;
}

// Round 7
// 385.036 us; speedup vs baseline: 1.0272x; 1.0272x over previous
//
#include <hip/hip_runtime.h>
#include <stdint.h>

#define FH 64
#define FW 64
#define CIN 1536
#define C3C 512
#define C4C 1024
#define COUT 512
#define BATCH 16
#define NPIX 4096
#define NBOX 10
#define MPAD 256   // 10 boxes * 25 bins = 250, padded
#define KT128 12   // CIN/128 K-tiles

// mega_pre flat-grid segments (fusedT blocks now cover a y-PAIR)
#define NB_FU 6144               // build_fusedT: 12 * 32 * 16
#define NB_P  4000               // build_P: 160*25
#define NB_W  768                // conv_w: 196608/256
#define NB_BN 2                  // prep_bn: 512/256
#define NB_CP 3                  // boxes->out copy: 640/256 rounded up
#define NB_TOT (NB_FU + NB_P + NB_W + NB_BN + NB_CP)

typedef float v4f __attribute__((ext_vector_type(4)));
typedef long  v2l __attribute__((ext_vector_type(2)));

#define GLOAD_LDS16(g, l) __builtin_amdgcn_global_load_lds( \
    (const __attribute__((address_space(1))) void*)(g),     \
    (__attribute__((address_space(3))) void*)(l), 16, 0, 0)

#define BARRIER() asm volatile("s_barrier" ::: "memory")

// pack 4 floats -> 4 fp8 e4m3 bytes in one u32 (byte k = f[k])
__device__ __forceinline__ uint32_t pack4_fp8(float a, float b, float c, float d) {
    int lo = __builtin_amdgcn_cvt_pk_fp8_f32(a, b, 0, false);
    int v  = __builtin_amdgcn_cvt_pk_fp8_f32(c, d, lo, true);
    return (uint32_t)v;
}
__device__ __forceinline__ unsigned char f32_to_fp8(float a) {
    return (unsigned char)(__builtin_amdgcn_cvt_pk_fp8_f32(a, a, 0, false) & 0xff);
}

// K-permutation within each 128-byte K-block of w8/fusedT:
// logical k7 stored at byte quad*32 + s*8 + b  (quad=(k7>>3)&3, s=k7>>5, b=k7&7).
// Makes each lane's MFMA operand pair {s,s+1} 16 contiguous bytes -> ds_read_b128.
// Applied identically to BOTH operands, so sum_k A[m][k]B[n][k] is preserved.

// ---------------- mega_pre: all input-only stages in ONE dispatch ----------
// fusedT segment rework (R6 post-mortem): kernel was outstanding-bytes
// limited (~6 x 16B loads in flight/wave -> Little's law caps at ~2.7 TB/s).
// Now: one block = y-PAIR, ALL loads hoisted to registers before packing
// (c3: 16 x float4/thread; c4: 24 x float2, bilinear row jy shared across
// the pair, -25% c4 reads). 4x inflight bytes -> ~2.5x BW.
__global__ __launch_bounds__(256) void mega_pre(
        const float* __restrict__ c3, const float* __restrict__ c4,
        const float* __restrict__ boxes,
        const float* __restrict__ w_conv, const float* __restrict__ b_conv,
        const float* __restrict__ bng, const float* __restrict__ bnb,
        const float* __restrict__ bnm, const float* __restrict__ bnv,
        unsigned char* __restrict__ fusedT, unsigned char* __restrict__ P,
        unsigned char* __restrict__ w8,
        float* __restrict__ scale, float* __restrict__ shift,
        float* __restrict__ out) {
    __shared__ uint32_t lds[2 * 64 * 36];
    const int bid = blockIdx.x;
    const int t   = threadIdx.x;

    if (bid < NB_FU) {
        int ct = bid % 12;            // 0..11; <4 -> c3, else c4
        int rest = bid / 12;
        int yj = rest & 31;           // y-pair index: y = 2*yj, 2*yj+1
        int b  = rest >> 5;
        int pg = t & 15;              // pixel quad: px 4pg..4pg+3
        int cq = t >> 4;              // 0..15; cquad = cq + 16r

        if (ct < 4) {
            // ---- c3 path: hoist all 16 float4 loads, then pack ----
            float4 f3[2][2][4];       // [yi][r][k]
            #pragma unroll
            for (int yi = 0; yi < 2; ++yi)
                #pragma unroll
                for (int r = 0; r < 2; ++r) {
                    int ch = ct * 128 + 4 * (cq + 16 * r);
                    const float* src = c3 + (((size_t)(b * C3C + ch) * FH + (2 * yj + yi)) * FW) + 4 * pg;
                    #pragma unroll
                    for (int k = 0; k < 4; ++k)
                        f3[yi][r][k] = *(const float4*)(src + (size_t)k * (FH * FW));
                }
            #pragma unroll
            for (int yi = 0; yi < 2; ++yi)
                #pragma unroll
                for (int r = 0; r < 2; ++r) {
                    int cquad = cq + 16 * r;
                    float vv[4][4];
                    #pragma unroll
                    for (int k = 0; k < 4; ++k) {
                        vv[k][0] = f3[yi][r][k].x; vv[k][1] = f3[yi][r][k].y;
                        vv[k][2] = f3[yi][r][k].z; vv[k][3] = f3[yi][r][k].w;
                    }
                    #pragma unroll
                    for (int i = 0; i < 4; ++i) {
                        int px = 4 * pg + i;
                        lds[yi * 2304 + px * 36 + 4 * ((cquad >> 2) ^ ((px >> 1) & 7)) + (cquad & 3)] =
                            pack4_fp8(vv[0][i], vv[1][i], vv[2][i], vv[3][i]);
                    }
                }
        } else {
            // ---- c4 path: rows {jy-1, jy, jy+1}; jy shared across the pair ----
            int jy  = yj;
            int rm1 = max(jy - 1, 0);
            int rp1 = min(jy + 1, 31);
            float2 g0[2][4], gm[2][4], gp[2][4];   // [r][k]
            #pragma unroll
            for (int r = 0; r < 2; ++r) {
                int ch = ct * 128 - 512 + 4 * (cq + 16 * r);
                const float* base = c4 + (size_t)(b * C4C + ch) * 1024;
                #pragma unroll
                for (int k = 0; k < 4; ++k) {
                    const float* pc = base + (size_t)k * 1024 + 2 * pg;
                    g0[r][k] = *(const float2*)(pc + jy * 32);
                    gm[r][k] = *(const float2*)(pc + rm1 * 32);
                    gp[r][k] = *(const float2*)(pc + rp1 * 32);
                }
            }
            #pragma unroll
            for (int yi = 0; yi < 2; ++yi)
                #pragma unroll
                for (int r = 0; r < 2; ++r) {
                    int cquad = cq + 16 * r;
                    float vv[4][4];
                    #pragma unroll
                    for (int k = 0; k < 4; ++k) {
                        float2 f0 = g0[r][k];
                        float2 f1 = yi ? gp[r][k] : gm[r][k];
                        float rbA = 0.75f * f0.x + 0.25f * f1.x;   // rb[2pg]
                        float rbB = 0.75f * f0.y + 0.25f * f1.y;   // rb[2pg+1]
                        float rbm = __shfl_up(rbB, 1, 16);          // rb[2pg-1]
                        float rbp = __shfl_down(rbA, 1, 16);        // rb[2pg+2]
                        if (pg == 0)  rbm = rbA;                    // km clamp
                        if (pg == 15) rbp = rbB;                    // kp clamp
                        vv[k][0] = 0.75f * rbA + 0.25f * rbm;
                        vv[k][1] = 0.75f * rbA + 0.25f * rbB;
                        vv[k][2] = 0.75f * rbB + 0.25f * rbA;
                        vv[k][3] = 0.75f * rbB + 0.25f * rbp;
                    }
                    #pragma unroll
                    for (int i = 0; i < 4; ++i) {
                        int px = 4 * pg + i;
                        lds[yi * 2304 + px * 36 + 4 * ((cquad >> 2) ^ ((px >> 1) & 7)) + (cquad & 3)] =
                            pack4_fp8(vv[0][i], vv[1][i], vv[2][i], vv[3][i]);
                    }
                }
        }
        __syncthreads();
        // write: 2 tiles x 64 px x 128 B; thread covers one 16-B logical chunk as 2x8B
        int g = t & 7;                 // 16-channel group
        #pragma unroll
        for (int yi = 0; yi < 2; ++yi)
            #pragma unroll
            for (int rr2 = 0; rr2 < 2; ++rr2) {
                int px = (t >> 3) + 32 * rr2;
                uint4 w = *(const uint4*)(&lds[yi * 2304 + px * 36 + 4 * (g ^ ((px >> 1) & 7))]);
                unsigned char* dst = fusedT + ((size_t)b * NPIX + (2 * yj + yi) * FW + px) * CIN + ct * 128;
                int pos0 = ((2 * g) & 3) * 32 + (g >> 1) * 8;
                int pos1 = ((2 * g + 1) & 3) * 32 + (g >> 1) * 8;
                *(uint2*)(dst + pos0) = make_uint2(w.x, w.y);
                *(uint2*)(dst + pos1) = make_uint2(w.z, w.w);
            }
    } else if (bid < NB_FU + NB_P) {
        // ---- build pooling matrix P[b][m][pix] fp8 (x64) ----
        int id  = bid - NB_FU;
        int br  = id % 160;
        int m25 = id / 160;
        int b   = br / NBOX;
        int m   = (br % NBOX) * 25 + m25;
        int p   = m25 / 5, q = m25 % 5;
        int y   = t >> 2;
        int x0  = (t & 3) * 16;
        const float* bx = boxes + (size_t)br * 4;
        int x1 = min(max((int)floorf(bx[0] * 0.125f), 0), 63);
        int y1 = min(max((int)floorf(bx[1] * 0.125f), 0), 63);
        int x2 = min(max((int)ceilf (bx[2] * 0.125f), 0), 63);
        int y2 = min(max((int)ceilf (bx[3] * 0.125f), 0), 63);
        if (x2 <= x1) x2 = min(x1 + 1, 64);
        if (y2 <= y1) y2 = min(y1 + 1, 64);
        int Lx = x2 - x1, Ly = y2 - y1;
        int sx = x1 + (q * Lx) / 5;
        int ex = x1 + ((q + 1) * Lx + 4) / 5;
        int sy = y1 + (p * Ly) / 5;
        int ey = y1 + ((p + 1) * Ly + 4) / 5;
        float wyv  = (y >= sy && y < ey) ? 1.0f / (float)(ey - sy) : 0.0f;
        float pval = 64.0f * wyv / (float)(ex - sx);
        float v[16];
        #pragma unroll
        for (int i = 0; i < 16; ++i) {
            int xi = x0 + i;
            v[i] = (xi >= sx && xi < ex) ? pval : 0.0f;
        }
        uint4 w;
        w.x = pack4_fp8(v[0],  v[1],  v[2],  v[3]);
        w.y = pack4_fp8(v[4],  v[5],  v[6],  v[7]);
        w.z = pack4_fp8(v[8],  v[9],  v[10], v[11]);
        w.w = pack4_fp8(v[12], v[13], v[14], v[15]);
        *(uint4*)(P + ((size_t)b * MPAD + m) * NPIX + y * FW + x0) = w;
    } else if (bid < NB_FU + NB_P + NB_W) {
        // ---- W f32 -> fp8 (x16), k-permuted layout ----
        int i = (bid - NB_FU - NB_P) * 256 + t;
        if (i < COUT * CIN / 4) {
            float4 f = *(const float4*)(w_conv + i * 4);
            uint32_t v = pack4_fp8(f.x * 16.0f, f.y * 16.0f, f.z * 16.0f, f.w * 16.0f);
            int c0 = (i * 4) % CIN;
            int o  = (i * 4) / CIN;
            int k7 = c0 & 127;
            int pos = ((k7 >> 3) & 3) * 32 + (k7 >> 5) * 8 + (k7 & 7);
            *(uint32_t*)(w8 + (size_t)o * CIN + (c0 & ~127) + pos) = v;
        }
    } else if (bid < NB_FU + NB_P + NB_W + NB_BN) {
        // ---- BN constant folding ----
        int o = (bid - NB_FU - NB_P - NB_W) * 256 + t;
        if (o < COUT) {
            float inv = bng[o] / sqrtf(bnv[o] + 1e-5f);
            scale[o] = inv * 0.0625f;             // /16: W quantized as W*16
            shift[o] = bnb[o] + inv * (b_conv[o] - bnm[o]);
        }
    } else {
        // ---- boxes -> out[0:640] copy (replaces hipMemcpyAsync) ----
        int i = (bid - NB_FU - NB_P - NB_W - NB_BN) * 256 + t;
        if (i < 640) out[i] = boxes[i];
    }
}

// ---------------- fp8 GEMM + BN + ReLU, 256x256 tile, BK=128, 2-phase ------
// k-permuted operands -> each fragment pair is one conflict-free
// ds_read_b128; counted vmcnt, raw s_barrier, setprio around MFMA.
__global__ __launch_bounds__(512, 2) void gemm_bn_relu(
        const unsigned char* __restrict__ w8,
        const unsigned char* __restrict__ fusedT,
        const float* __restrict__ scale, const float* __restrict__ shift,
        unsigned char* __restrict__ attr) {
    __shared__ __align__(16) unsigned char lds_a[2][32768];
    __shared__ __align__(16) unsigned char lds_b[2][32768];
    const int t  = threadIdx.x;
    const int n0 = blockIdx.x * 256;   // pixel tile
    const int o0 = blockIdx.y * 256;   // out-channel tile
    const int b  = blockIdx.z;
    const int wave = t >> 6, lane = t & 63;
    const int wm = wave & 1, wn = wave >> 1;   // 2 x 4 wave grid
    const int quad = lane >> 4, l16 = lane & 15;
    // b128 chunk offsets: chunk c = quad*2+h stored at (c ^ (row&7)); row&7 = l16&7
    const int cp0 = (((quad << 1) ^ (l16 & 7)) << 4);
    const int cp1 = cp0 ^ 16;
    const unsigned char* fb = fusedT + (size_t)b * NPIX * CIN;

    // ---- staging: 512 threads cover one 64row x 128B unit ----
    const int rr = t >> 3;                        // row within unit (0..63)
    const int cg = (t & 7) ^ (rr & 7);            // inverse-swizzled src chunk
    const unsigned char* gA = w8 + (size_t)(o0 + rr) * CIN + cg * 16;
    const unsigned char* gB = fb + (size_t)(n0 + rr) * CIN + cg * 16;

#define SA(u, kt, d) GLOAD_LDS16(gA + (size_t)(u) * (64 * CIN) + (kt) * 128, \
                                 &lds_a[d][(u) * 8192 + t * 16])
#define SB(u, kt, d) GLOAD_LDS16(gB + (size_t)(u) * (64 * CIN) + (kt) * 128, \
                                 &lds_b[d][(u) * 8192 + t * 16])
#define RAV(d, ph, i, cp) (*(const v2l*)(&lds_a[d][((wm * 128 + (ph) * 64 + (i) * 16 + l16) << 7) + (cp)]))
#define RBV(d, j, cp)     (*(const v2l*)(&lds_b[d][((wn * 64 + (j) * 16 + l16) << 7) + (cp)]))

    v4f acc[8][4];   // [ph*4+i][j]
    #pragma unroll
    for (int i = 0; i < 8; ++i)
        #pragma unroll
        for (int j = 0; j < 4; ++j) acc[i][j] = (v4f)0.0f;

    // ---- prologue: tile0 full (8 units) + S1(tile1) (6 units) ----
    SA(0, 0, 0); SA(1, 0, 0); SA(2, 0, 0); SA(3, 0, 0);
    SB(0, 0, 0); SB(1, 0, 0); SB(2, 0, 0); SB(3, 0, 0);
    SA(0, 1, 1); SA(2, 1, 1); SB(0, 1, 1); SB(1, 1, 1); SB(2, 1, 1); SB(3, 1, 1);
    asm volatile("s_waitcnt vmcnt(6)" ::: "memory");
    BARRIER();

    v2l ah0[4], ah1[4], bh0[4], bh1[4];

    for (int kt = 0; kt < KT128; ++kt) {
        const int cur = kt & 1, nxt = cur ^ 1;

        // ---- phase 1: A rows wm*128..+64 x all B ----
        #pragma unroll
        for (int i = 0; i < 4; ++i) { ah0[i] = RAV(cur, 0, i, cp0); ah1[i] = RAV(cur, 0, i, cp1); }
        #pragma unroll
        for (int j = 0; j < 4; ++j) { bh0[j] = RBV(cur, j, cp0); bh1[j] = RBV(cur, j, cp1); }
        if (kt > 0 && kt + 1 < KT128) {
            SA(0, kt + 1, nxt); SA(2, kt + 1, nxt);
            SB(0, kt + 1, nxt); SB(1, kt + 1, nxt);
            SB(2, kt + 1, nxt); SB(3, kt + 1, nxt);
        }
        __builtin_amdgcn_s_setprio(1);
        #pragma unroll
        for (int s = 0; s < 2; ++s)
            #pragma unroll
            for (int i = 0; i < 4; ++i)
                #pragma unroll
                for (int j = 0; j < 4; ++j)
                    acc[i][j] = __builtin_amdgcn_mfma_f32_16x16x32_fp8_fp8(ah0[i][s], bh0[j][s], acc[i][j], 0, 0, 0);
        #pragma unroll
        for (int s = 0; s < 2; ++s)
            #pragma unroll
            for (int i = 0; i < 4; ++i)
                #pragma unroll
                for (int j = 0; j < 4; ++j)
                    acc[i][j] = __builtin_amdgcn_mfma_f32_16x16x32_fp8_fp8(ah1[i][s], bh1[j][s], acc[i][j], 0, 0, 0);
        __builtin_amdgcn_s_setprio(0);
        if (kt + 1 < KT128) { asm volatile("s_waitcnt vmcnt(6)" ::: "memory"); }
        else               { asm volatile("s_waitcnt vmcnt(0)" ::: "memory"); }
        BARRIER();

        // ---- phase 2: A rows wm*128+64..+128 (B frags reused) ----
        #pragma unroll
        for (int i = 0; i < 4; ++i) { ah0[i] = RAV(cur, 1, i, cp0); ah1[i] = RAV(cur, 1, i, cp1); }
        if (kt + 1 < KT128) { SA(1, kt + 1, nxt); SA(3, kt + 1, nxt); }
        __builtin_amdgcn_s_setprio(1);
        #pragma unroll
        for (int s = 0; s < 2; ++s)
            #pragma unroll
            for (int i = 0; i < 4; ++i)
                #pragma unroll
                for (int j = 0; j < 4; ++j)
                    acc[4 + i][j] = __builtin_amdgcn_mfma_f32_16x16x32_fp8_fp8(ah0[i][s], bh0[j][s], acc[4 + i][j], 0, 0, 0);
        #pragma unroll
        for (int s = 0; s < 2; ++s)
            #pragma unroll
            for (int i = 0; i < 4; ++i)
                #pragma unroll
                for (int j = 0; j < 4; ++j)
                    acc[4 + i][j] = __builtin_amdgcn_mfma_f32_16x16x32_fp8_fp8(ah1[i][s], bh1[j][s], acc[4 + i][j], 0, 0, 0);
        __builtin_amdgcn_s_setprio(0);
        if (kt + 1 < KT128) { asm volatile("s_waitcnt vmcnt(2)" ::: "memory"); }
        BARRIER();
    }

    // ---- epilogue: BN + ReLU + fp8 channel-major store ----
    unsigned char* ab = attr + (size_t)b * COUT * NPIX;
    #pragma unroll
    for (int a = 0; a < 8; ++a) {
        int obase = o0 + wm * 128 + (a >> 2) * 64 + (a & 3) * 16 + quad * 4;
        #pragma unroll
        for (int r = 0; r < 4; ++r) {
            int oo = obase + r;
            float sc = scale[oo], sh = shift[oo];
            #pragma unroll
            for (int j = 0; j < 4; ++j) {
                int n = n0 + wn * 64 + j * 16 + l16;
                float v = fmaxf(acc[a][j][r] * sc + sh, 0.0f);
                ab[(size_t)oo * NPIX + n] = f32_to_fp8(v);
            }
        }
    }
#undef SA
#undef SB
#undef RAV
#undef RBV
}

// ---------------- fp8 pool GEMM, K-split x4, dense partials ----------------
// Restored from the verified R5 lineage: 512 blocks (2/CU) overlap the
// per-K-step staging latency; the 128-block fused variant left half the
// CUs idle. Dispatch-count cost is ~0 (measured R5->R6).
__global__ __launch_bounds__(256) void pool_gemm(
        const unsigned char* __restrict__ P,
        const unsigned char* __restrict__ attr,
        float* __restrict__ part2) {
    __shared__ __align__(16) unsigned char lds_a[128 * 64];
    __shared__ __align__(16) unsigned char lds_b[128 * 64];
    int t  = threadIdx.x;
    int m0 = blockIdx.x * 128;
    int c0 = (blockIdx.y & 3) * 128;
    int seg = blockIdx.y >> 2;
    int b  = blockIdx.z;
    int wave = t >> 6, lane = t & 63;
    int wm = wave & 1, wn = wave >> 1;
    int quad = lane >> 4, l16 = lane & 15;
    const unsigned char* Pb = P + (size_t)b * MPAD * NPIX + seg * 1024;
    const unsigned char* ab = attr + (size_t)b * COUT * NPIX + seg * 1024;

    v4f acc[4][4];
    #pragma unroll
    for (int i = 0; i < 4; ++i)
        #pragma unroll
        for (int j = 0; j < 4; ++j) acc[i][j] = (v4f)0.0f;

    int row = t >> 2;
    int cg  = (t & 3) ^ ((row >> 1) & 3);
    const unsigned char* ga0 = Pb + (size_t)(m0 + row) * NPIX + cg * 16;
    const unsigned char* ga1 = Pb + (size_t)(m0 + row + 64) * NPIX + cg * 16;
    const unsigned char* gb0 = ab + (size_t)(c0 + row) * NPIX + cg * 16;
    const unsigned char* gb1 = ab + (size_t)(c0 + row + 64) * NPIX + cg * 16;
    unsigned char* la0 = lds_a + t * 16;
    unsigned char* la1 = lds_a + 4096 + t * 16;
    unsigned char* lb0 = lds_b + t * 16;
    unsigned char* lb1 = lds_b + 4096 + t * 16;

    int ra[4], rb[4];
    #pragma unroll
    for (int i = 0; i < 4; ++i) { ra[i] = wm * 64 + i * 16 + l16; rb[i] = wn * 64 + i * 16 + l16; }
    int q2 = quad >> 1, q1 = (quad & 1) * 8;

    for (int kt = 0; kt < 1024 / 64; ++kt) {
        __syncthreads();
        GLOAD_LDS16(ga0, la0);
        GLOAD_LDS16(ga1, la1);
        GLOAD_LDS16(gb0, lb0);
        GLOAD_LDS16(gb1, lb1);
        ga0 += 64; ga1 += 64; gb0 += 64; gb1 += 64;
        __syncthreads();

        #pragma unroll
        for (int s = 0; s < 2; ++s) {
            long af[4], bf[4];
            #pragma unroll
            for (int i = 0; i < 4; ++i) {
                int pa = (2 * s + q2) ^ ((ra[i] >> 1) & 3);
                af[i] = *(const long*)(lds_a + ra[i] * 64 + pa * 16 + q1);
                int pb = (2 * s + q2) ^ ((rb[i] >> 1) & 3);
                bf[i] = *(const long*)(lds_b + rb[i] * 64 + pb * 16 + q1);
            }
            #pragma unroll
            for (int i = 0; i < 4; ++i)
                #pragma unroll
                for (int j = 0; j < 4; ++j)
                    acc[i][j] = __builtin_amdgcn_mfma_f32_16x16x32_fp8_fp8(af[i], bf[j], acc[i][j], 0, 0, 0);
        }
    }

    float* pp = part2 + (((size_t)seg * BATCH + b) * MPAD) * COUT;
    #pragma unroll
    for (int i = 0; i < 4; ++i) {
        #pragma unroll
        for (int r = 0; r < 4; ++r) {
            int mrow = m0 + wm * 64 + i * 16 + quad * 4 + r;
            #pragma unroll
            for (int j = 0; j < 4; ++j) {
                int c = c0 + wn * 64 + j * 16 + l16;
                pp[(size_t)mrow * COUT + c] = acc[i][j][r];
            }
        }
    }
}

// ---------------- reduce 4 segs (/64 for P scaling), transpose to out ------
__global__ __launch_bounds__(256) void pool_reduce(const float* __restrict__ part2,
                                                   float* __restrict__ out) {
    const size_t SEG = (size_t)BATCH * MPAD * COUT;
    int i = blockIdx.x * 256 + threadIdx.x;
    int c = i & (COUT - 1);
    int m = (i >> 9) & (MPAD - 1);
    int b = i >> 17;
    if (m >= 250) return;
    float s = part2[i] + part2[i + SEG] + part2[i + 2 * SEG] + part2[i + 3 * SEG];
    int box = m / 25, bin = m - box * 25;
    out[640 + ((size_t)(b * NBOX + box) * COUT + c) * 25 + bin] = s * 0.015625f;
}

extern "C" void kernel_launch(void* const* d_in, const int* in_sizes, int n_in,
                              void* d_out, int out_size, void* d_ws, size_t ws_size,
                              hipStream_t stream) {
    const float* c3     = (const float*)d_in[0];
    const float* c4     = (const float*)d_in[1];
    const float* boxes  = (const float*)d_in[2];
    const float* w_conv = (const float*)d_in[3];
    const float* b_conv = (const float*)d_in[4];
    const float* bng    = (const float*)d_in[5];
    const float* bnb    = (const float*)d_in[6];
    const float* bnm    = (const float*)d_in[7];
    const float* bnv    = (const float*)d_in[8];
    float* out = (float*)d_out;

    char* ws = (char*)d_ws;
    // fp8 layout (no aliasing needed):
    unsigned char* fusedT = (unsigned char*)ws;                 // 100663296 B
    unsigned char* P      = (unsigned char*)(ws + 100663296);   //  16777216 B
    float*         part2  = (float*)(ws + 117440512);           //  33554432 B
    unsigned char* w8     = (unsigned char*)(ws + 150994944);   //    786432 B
    float*         scale  = (float*)(ws + 151781376);           //      2048 B
    float*         shift  = (float*)(ws + 151783424);           //      2048 B
    unsigned char* attr   = (unsigned char*)(ws + 151785472);   //  33554432 B

    mega_pre<<<NB_TOT, 256, 0, stream>>>(c3, c4, boxes, w_conv, b_conv,
                                         bng, bnb, bnm, bnv,
                                         fusedT, P, w8, scale, shift, out);
    gemm_bn_relu<<<dim3(16, 2, 16), 512, 0, stream>>>(w8, fusedT, scale, shift, attr);
    pool_gemm<<<dim3(2, 16, 16), 256, 0, stream>>>(P, attr, part2);
    pool_reduce<<<(BATCH * MPAD * COUT) / 256, 256, 0, stream>>>(part2, out);
    (void)in_sizes; (void)n_in; (void)out_size; (void)ws_size;
}

// Round 8
// 379.473 us; speedup vs baseline: 1.0422x; 1.0147x over previous
//
#include <hip/hip_runtime.h>
#include <stdint.h>

#define FH 64
#define FW 64
#define CIN 1536
#define C3C 512
#define C4C 1024
#define COUT 512
#define BATCH 16
#define NPIX 4096
#define NBOX 10
#define MPAD 256   // 10 boxes * 25 bins = 250, padded
#define KT128 12   // CIN/128 K-tiles

// mega_pre flat-grid segments
#define NB_FU 12288              // build_fusedT: 12*64*16 (single-y blocks)
#define NB_P  4000               // build_P: 160*25
#define NB_W  768                // conv_w: 196608/256
#define NB_BN 2                  // prep_bn: 512/256
#define NB_CP 3                  // boxes->out copy: 640/256 rounded up
#define NB_TOT (NB_FU + NB_P + NB_W + NB_BN + NB_CP)

typedef float v4f __attribute__((ext_vector_type(4)));
typedef long  v2l __attribute__((ext_vector_type(2)));

#define GLOAD_LDS16(g, l) __builtin_amdgcn_global_load_lds( \
    (const __attribute__((address_space(1))) void*)(g),     \
    (__attribute__((address_space(3))) void*)(l), 16, 0, 0)

#define BARRIER() asm volatile("s_barrier" ::: "memory")

// pack 4 floats -> 4 fp8 e4m3 bytes in one u32 (byte k = f[k])
__device__ __forceinline__ uint32_t pack4_fp8(float a, float b, float c, float d) {
    int lo = __builtin_amdgcn_cvt_pk_fp8_f32(a, b, 0, false);
    int v  = __builtin_amdgcn_cvt_pk_fp8_f32(c, d, lo, true);
    return (uint32_t)v;
}
__device__ __forceinline__ unsigned char f32_to_fp8(float a) {
    return (unsigned char)(__builtin_amdgcn_cvt_pk_fp8_f32(a, a, 0, false) & 0xff);
}

// K-permutation within each 128-byte K-block of w8/fusedT:
// logical k7 stored at byte quad*32 + s*8 + b  (quad=(k7>>3)&3, s=k7>>5, b=k7&7).
// Makes each lane's MFMA operand pair {s,s+1} 16 contiguous bytes -> ds_read_b128.
// Applied identically to BOTH operands, so sum_k A[m][k]B[n][k] is preserved.
// Word-level bijection: channel-word cquad lands at word index
//   w'(cquad) = ((cquad>>1)&3)*8 + (cquad>>3)*2 + (cquad&1)   (bits [c2 c1 c4 c3 c0])

// ---------------- mega_pre: all input-only stages in ONE dispatch ----------
// R7 post-mortem: load-side changes (R6 shallow/81% occ vs R7 deep/58% occ)
// both hit 2.6 TB/s -> store path (constant between them) is the limiter.
// Fix: store packed words into LDS at PERMUTED word index w', so the global
// writer emits ONE 16-B store per chunk (was 2x8-B scattered) -- byte-exact
// same fusedT image, half the store instructions, 1024 B/wave-instr.
__global__ __launch_bounds__(256) void mega_pre(
        const float* __restrict__ c3, const float* __restrict__ c4,
        const float* __restrict__ boxes,
        const float* __restrict__ w_conv, const float* __restrict__ b_conv,
        const float* __restrict__ bng, const float* __restrict__ bnb,
        const float* __restrict__ bnm, const float* __restrict__ bnv,
        unsigned char* __restrict__ fusedT, unsigned char* __restrict__ P,
        unsigned char* __restrict__ w8,
        float* __restrict__ scale, float* __restrict__ shift,
        float* __restrict__ out) {
    __shared__ uint32_t lds[64 * 36];
    const int bid = blockIdx.x;
    const int t   = threadIdx.x;

    if (bid < NB_FU) {
        int ct = bid % 12;            // 0..11; <4 -> c3, else c4
        int rest = bid / 12;
        int y  = rest & 63;
        int b  = rest >> 6;
        int pg = t & 15;              // pixel quad: px 4pg..4pg+3
        int cq = t >> 4;              // 0..15; cquad = cq + 16r

        #pragma unroll
        for (int r = 0; r < 2; ++r) {
            int cquad = cq + 16 * r;
            float vv[4][4];           // [channel][pixel]
            if (ct < 4) {
                int ch = ct * 128 + 4 * cquad;
                const float* src = c3 + (((size_t)(b * C3C + ch) * FH + y) * FW) + 4 * pg;
                #pragma unroll
                for (int k = 0; k < 4; ++k) {
                    float4 f = *(const float4*)(src + (size_t)k * (FH * FW));
                    vv[k][0] = f.x; vv[k][1] = f.y; vv[k][2] = f.z; vv[k][3] = f.w;
                }
            } else {
                int ch = ct * 128 - 512 + 4 * cquad;
                int jy = y >> 1;
                int jyB = min(max(jy + ((y & 1) ? 1 : -1), 0), 31);
                const float* base = c4 + (size_t)(b * C4C + ch) * 1024;
                #pragma unroll
                for (int k = 0; k < 4; ++k) {
                    const float* pc = base + (size_t)k * 1024;
                    float2 f0 = *(const float2*)(pc + jy * 32 + 2 * pg);
                    float2 f1 = *(const float2*)(pc + jyB * 32 + 2 * pg);
                    float rbA = 0.75f * f0.x + 0.25f * f1.x;   // rb[2pg]
                    float rbB = 0.75f * f0.y + 0.25f * f1.y;   // rb[2pg+1]
                    float rbm = __shfl_up(rbB, 1, 16);          // rb[2pg-1]
                    float rbp = __shfl_down(rbA, 1, 16);        // rb[2pg+2]
                    if (pg == 0)  rbm = rbA;                    // km clamp
                    if (pg == 15) rbp = rbB;                    // kp clamp
                    vv[k][0] = 0.75f * rbA + 0.25f * rbm;
                    vv[k][1] = 0.75f * rbA + 0.25f * rbB;
                    vv[k][2] = 0.75f * rbB + 0.25f * rbA;
                    vv[k][3] = 0.75f * rbB + 0.25f * rbp;
                }
            }
            // permuted word index (bits [c2 c1 c4 c3 c0] of cquad)
            int wp = ((cquad >> 1) & 3) * 8 + (cquad >> 3) * 2 + (cquad & 1);
            #pragma unroll
            for (int i = 0; i < 4; ++i) {
                int px = 4 * pg + i;
                lds[px * 36 + 4 * ((wp >> 2) ^ ((px >> 1) & 7)) + (wp & 3)] =
                    pack4_fp8(vv[0][i], vv[1][i], vv[2][i], vv[3][i]);
            }
        }
        __syncthreads();
        // write: 64 px x 128 B; thread covers one 16-B permuted chunk
        int g = t & 7;
        #pragma unroll
        for (int rr2 = 0; rr2 < 2; ++rr2) {
            int px = (t >> 3) + 32 * rr2;
            uint4 w = *(const uint4*)(&lds[px * 36 + 4 * (g ^ ((px >> 1) & 7))]);
            *(uint4*)(fusedT + ((size_t)b * NPIX + y * FW + px) * CIN + ct * 128 + g * 16) = w;
        }
    } else if (bid < NB_FU + NB_P) {
        // ---- build pooling matrix P[b][m][pix] fp8 (x64) ----
        int id  = bid - NB_FU;
        int br  = id % 160;
        int m25 = id / 160;
        int b   = br / NBOX;
        int m   = (br % NBOX) * 25 + m25;
        int p   = m25 / 5, q = m25 % 5;
        int y   = t >> 2;
        int x0  = (t & 3) * 16;
        const float* bx = boxes + (size_t)br * 4;
        int x1 = min(max((int)floorf(bx[0] * 0.125f), 0), 63);
        int y1 = min(max((int)floorf(bx[1] * 0.125f), 0), 63);
        int x2 = min(max((int)ceilf (bx[2] * 0.125f), 0), 63);
        int y2 = min(max((int)ceilf (bx[3] * 0.125f), 0), 63);
        if (x2 <= x1) x2 = min(x1 + 1, 64);
        if (y2 <= y1) y2 = min(y1 + 1, 64);
        int Lx = x2 - x1, Ly = y2 - y1;
        int sx = x1 + (q * Lx) / 5;
        int ex = x1 + ((q + 1) * Lx + 4) / 5;
        int sy = y1 + (p * Ly) / 5;
        int ey = y1 + ((p + 1) * Ly + 4) / 5;
        float wyv  = (y >= sy && y < ey) ? 1.0f / (float)(ey - sy) : 0.0f;
        float pval = 64.0f * wyv / (float)(ex - sx);
        float v[16];
        #pragma unroll
        for (int i = 0; i < 16; ++i) {
            int xi = x0 + i;
            v[i] = (xi >= sx && xi < ex) ? pval : 0.0f;
        }
        uint4 w;
        w.x = pack4_fp8(v[0],  v[1],  v[2],  v[3]);
        w.y = pack4_fp8(v[4],  v[5],  v[6],  v[7]);
        w.z = pack4_fp8(v[8],  v[9],  v[10], v[11]);
        w.w = pack4_fp8(v[12], v[13], v[14], v[15]);
        *(uint4*)(P + ((size_t)b * MPAD + m) * NPIX + y * FW + x0) = w;
    } else if (bid < NB_FU + NB_P + NB_W) {
        // ---- W f32 -> fp8 (x16), k-permuted layout ----
        int i = (bid - NB_FU - NB_P) * 256 + t;
        if (i < COUT * CIN / 4) {
            float4 f = *(const float4*)(w_conv + i * 4);
            uint32_t v = pack4_fp8(f.x * 16.0f, f.y * 16.0f, f.z * 16.0f, f.w * 16.0f);
            int c0 = (i * 4) % CIN;
            int o  = (i * 4) / CIN;
            int k7 = c0 & 127;
            int pos = ((k7 >> 3) & 3) * 32 + (k7 >> 5) * 8 + (k7 & 7);
            *(uint32_t*)(w8 + (size_t)o * CIN + (c0 & ~127) + pos) = v;
        }
    } else if (bid < NB_FU + NB_P + NB_W + NB_BN) {
        // ---- BN constant folding ----
        int o = (bid - NB_FU - NB_P - NB_W) * 256 + t;
        if (o < COUT) {
            float inv = bng[o] / sqrtf(bnv[o] + 1e-5f);
            scale[o] = inv * 0.0625f;             // /16: W quantized as W*16
            shift[o] = bnb[o] + inv * (b_conv[o] - bnm[o]);
        }
    } else {
        // ---- boxes -> out[0:640] copy (replaces hipMemcpyAsync) ----
        int i = (bid - NB_FU - NB_P - NB_W - NB_BN) * 256 + t;
        if (i < 640) out[i] = boxes[i];
    }
}

// ---------------- fp8 GEMM + BN + ReLU, 256x256 tile, BK=128, 2-phase ------
// k-permuted operands -> each fragment pair is one conflict-free
// ds_read_b128; counted vmcnt, raw s_barrier, setprio around MFMA.
__global__ __launch_bounds__(512, 2) void gemm_bn_relu(
        const unsigned char* __restrict__ w8,
        const unsigned char* __restrict__ fusedT,
        const float* __restrict__ scale, const float* __restrict__ shift,
        unsigned char* __restrict__ attr) {
    __shared__ __align__(16) unsigned char lds_a[2][32768];
    __shared__ __align__(16) unsigned char lds_b[2][32768];
    const int t  = threadIdx.x;
    const int n0 = blockIdx.x * 256;   // pixel tile
    const int o0 = blockIdx.y * 256;   // out-channel tile
    const int b  = blockIdx.z;
    const int wave = t >> 6, lane = t & 63;
    const int wm = wave & 1, wn = wave >> 1;   // 2 x 4 wave grid
    const int quad = lane >> 4, l16 = lane & 15;
    // b128 chunk offsets: chunk c = quad*2+h stored at (c ^ (row&7)); row&7 = l16&7
    const int cp0 = (((quad << 1) ^ (l16 & 7)) << 4);
    const int cp1 = cp0 ^ 16;
    const unsigned char* fb = fusedT + (size_t)b * NPIX * CIN;

    // ---- staging: 512 threads cover one 64row x 128B unit ----
    const int rr = t >> 3;                        // row within unit (0..63)
    const int cg = (t & 7) ^ (rr & 7);            // inverse-swizzled src chunk
    const unsigned char* gA = w8 + (size_t)(o0 + rr) * CIN + cg * 16;
    const unsigned char* gB = fb + (size_t)(n0 + rr) * CIN + cg * 16;

#define SA(u, kt, d) GLOAD_LDS16(gA + (size_t)(u) * (64 * CIN) + (kt) * 128, \
                                 &lds_a[d][(u) * 8192 + t * 16])
#define SB(u, kt, d) GLOAD_LDS16(gB + (size_t)(u) * (64 * CIN) + (kt) * 128, \
                                 &lds_b[d][(u) * 8192 + t * 16])
#define RAV(d, ph, i, cp) (*(const v2l*)(&lds_a[d][((wm * 128 + (ph) * 64 + (i) * 16 + l16) << 7) + (cp)]))
#define RBV(d, j, cp)     (*(const v2l*)(&lds_b[d][((wn * 64 + (j) * 16 + l16) << 7) + (cp)]))

    v4f acc[8][4];   // [ph*4+i][j]
    #pragma unroll
    for (int i = 0; i < 8; ++i)
        #pragma unroll
        for (int j = 0; j < 4; ++j) acc[i][j] = (v4f)0.0f;

    // ---- prologue: tile0 full (8 units) + S1(tile1) (6 units) ----
    SA(0, 0, 0); SA(1, 0, 0); SA(2, 0, 0); SA(3, 0, 0);
    SB(0, 0, 0); SB(1, 0, 0); SB(2, 0, 0); SB(3, 0, 0);
    SA(0, 1, 1); SA(2, 1, 1); SB(0, 1, 1); SB(1, 1, 1); SB(2, 1, 1); SB(3, 1, 1);
    asm volatile("s_waitcnt vmcnt(6)" ::: "memory");
    BARRIER();

    v2l ah0[4], ah1[4], bh0[4], bh1[4];

    for (int kt = 0; kt < KT128; ++kt) {
        const int cur = kt & 1, nxt = cur ^ 1;

        // ---- phase 1: A rows wm*128..+64 x all B ----
        #pragma unroll
        for (int i = 0; i < 4; ++i) { ah0[i] = RAV(cur, 0, i, cp0); ah1[i] = RAV(cur, 0, i, cp1); }
        #pragma unroll
        for (int j = 0; j < 4; ++j) { bh0[j] = RBV(cur, j, cp0); bh1[j] = RBV(cur, j, cp1); }
        if (kt > 0 && kt + 1 < KT128) {
            SA(0, kt + 1, nxt); SA(2, kt + 1, nxt);
            SB(0, kt + 1, nxt); SB(1, kt + 1, nxt);
            SB(2, kt + 1, nxt); SB(3, kt + 1, nxt);
        }
        __builtin_amdgcn_s_setprio(1);
        #pragma unroll
        for (int s = 0; s < 2; ++s)
            #pragma unroll
            for (int i = 0; i < 4; ++i)
                #pragma unroll
                for (int j = 0; j < 4; ++j)
                    acc[i][j] = __builtin_amdgcn_mfma_f32_16x16x32_fp8_fp8(ah0[i][s], bh0[j][s], acc[i][j], 0, 0, 0);
        #pragma unroll
        for (int s = 0; s < 2; ++s)
            #pragma unroll
            for (int i = 0; i < 4; ++i)
                #pragma unroll
                for (int j = 0; j < 4; ++j)
                    acc[i][j] = __builtin_amdgcn_mfma_f32_16x16x32_fp8_fp8(ah1[i][s], bh1[j][s], acc[i][j], 0, 0, 0);
        __builtin_amdgcn_s_setprio(0);
        if (kt + 1 < KT128) { asm volatile("s_waitcnt vmcnt(6)" ::: "memory"); }
        else               { asm volatile("s_waitcnt vmcnt(0)" ::: "memory"); }
        BARRIER();

        // ---- phase 2: A rows wm*128+64..+128 (B frags reused) ----
        #pragma unroll
        for (int i = 0; i < 4; ++i) { ah0[i] = RAV(cur, 1, i, cp0); ah1[i] = RAV(cur, 1, i, cp1); }
        if (kt + 1 < KT128) { SA(1, kt + 1, nxt); SA(3, kt + 1, nxt); }
        __builtin_amdgcn_s_setprio(1);
        #pragma unroll
        for (int s = 0; s < 2; ++s)
            #pragma unroll
            for (int i = 0; i < 4; ++i)
                #pragma unroll
                for (int j = 0; j < 4; ++j)
                    acc[4 + i][j] = __builtin_amdgcn_mfma_f32_16x16x32_fp8_fp8(ah0[i][s], bh0[j][s], acc[4 + i][j], 0, 0, 0);
        #pragma unroll
        for (int s = 0; s < 2; ++s)
            #pragma unroll
            for (int i = 0; i < 4; ++i)
                #pragma unroll
                for (int j = 0; j < 4; ++j)
                    acc[4 + i][j] = __builtin_amdgcn_mfma_f32_16x16x32_fp8_fp8(ah1[i][s], bh1[j][s], acc[4 + i][j], 0, 0, 0);
        __builtin_amdgcn_s_setprio(0);
        if (kt + 1 < KT128) { asm volatile("s_waitcnt vmcnt(2)" ::: "memory"); }
        BARRIER();
    }

    // ---- epilogue: BN + ReLU + fp8 channel-major store ----
    unsigned char* ab = attr + (size_t)b * COUT * NPIX;
    #pragma unroll
    for (int a = 0; a < 8; ++a) {
        int obase = o0 + wm * 128 + (a >> 2) * 64 + (a & 3) * 16 + quad * 4;
        #pragma unroll
        for (int r = 0; r < 4; ++r) {
            int oo = obase + r;
            float sc = scale[oo], sh = shift[oo];
            #pragma unroll
            for (int j = 0; j < 4; ++j) {
                int n = n0 + wn * 64 + j * 16 + l16;
                float v = fmaxf(acc[a][j][r] * sc + sh, 0.0f);
                ab[(size_t)oo * NPIX + n] = f32_to_fp8(v);
            }
        }
    }
#undef SA
#undef SB
#undef RAV
#undef RBV
}

// ---------------- fp8 pool GEMM, K-split x4, dense partials ----------------
__global__ __launch_bounds__(256) void pool_gemm(
        const unsigned char* __restrict__ P,
        const unsigned char* __restrict__ attr,
        float* __restrict__ part2) {
    __shared__ __align__(16) unsigned char lds_a[128 * 64];
    __shared__ __align__(16) unsigned char lds_b[128 * 64];
    int t  = threadIdx.x;
    int m0 = blockIdx.x * 128;
    int c0 = (blockIdx.y & 3) * 128;
    int seg = blockIdx.y >> 2;
    int b  = blockIdx.z;
    int wave = t >> 6, lane = t & 63;
    int wm = wave & 1, wn = wave >> 1;
    int quad = lane >> 4, l16 = lane & 15;
    const unsigned char* Pb = P + (size_t)b * MPAD * NPIX + seg * 1024;
    const unsigned char* ab = attr + (size_t)b * COUT * NPIX + seg * 1024;

    v4f acc[4][4];
    #pragma unroll
    for (int i = 0; i < 4; ++i)
        #pragma unroll
        for (int j = 0; j < 4; ++j) acc[i][j] = (v4f)0.0f;

    int row = t >> 2;
    int cg  = (t & 3) ^ ((row >> 1) & 3);
    const unsigned char* ga0 = Pb + (size_t)(m0 + row) * NPIX + cg * 16;
    const unsigned char* ga1 = Pb + (size_t)(m0 + row + 64) * NPIX + cg * 16;
    const unsigned char* gb0 = ab + (size_t)(c0 + row) * NPIX + cg * 16;
    const unsigned char* gb1 = ab + (size_t)(c0 + row + 64) * NPIX + cg * 16;
    unsigned char* la0 = lds_a + t * 16;
    unsigned char* la1 = lds_a + 4096 + t * 16;
    unsigned char* lb0 = lds_b + t * 16;
    unsigned char* lb1 = lds_b + 4096 + t * 16;

    int ra[4], rb[4];
    #pragma unroll
    for (int i = 0; i < 4; ++i) { ra[i] = wm * 64 + i * 16 + l16; rb[i] = wn * 64 + i * 16 + l16; }
    int q2 = quad >> 1, q1 = (quad & 1) * 8;

    for (int kt = 0; kt < 1024 / 64; ++kt) {
        __syncthreads();
        GLOAD_LDS16(ga0, la0);
        GLOAD_LDS16(ga1, la1);
        GLOAD_LDS16(gb0, lb0);
        GLOAD_LDS16(gb1, lb1);
        ga0 += 64; ga1 += 64; gb0 += 64; gb1 += 64;
        __syncthreads();

        #pragma unroll
        for (int s = 0; s < 2; ++s) {
            long af[4], bf[4];
            #pragma unroll
            for (int i = 0; i < 4; ++i) {
                int pa = (2 * s + q2) ^ ((ra[i] >> 1) & 3);
                af[i] = *(const long*)(lds_a + ra[i] * 64 + pa * 16 + q1);
                int pb = (2 * s + q2) ^ ((rb[i] >> 1) & 3);
                bf[i] = *(const long*)(lds_b + rb[i] * 64 + pb * 16 + q1);
            }
            #pragma unroll
            for (int i = 0; i < 4; ++i)
                #pragma unroll
                for (int j = 0; j < 4; ++j)
                    acc[i][j] = __builtin_amdgcn_mfma_f32_16x16x32_fp8_fp8(af[i], bf[j], acc[i][j], 0, 0, 0);
        }
    }

    float* pp = part2 + (((size_t)seg * BATCH + b) * MPAD) * COUT;
    #pragma unroll
    for (int i = 0; i < 4; ++i) {
        #pragma unroll
        for (int r = 0; r < 4; ++r) {
            int mrow = m0 + wm * 64 + i * 16 + quad * 4 + r;
            #pragma unroll
            for (int j = 0; j < 4; ++j) {
                int c = c0 + wn * 64 + j * 16 + l16;
                pp[(size_t)mrow * COUT + c] = acc[i][j][r];
            }
        }
    }
}

// ---------------- reduce 4 segs (/64 for P scaling), transpose to out ------
__global__ __launch_bounds__(256) void pool_reduce(const float* __restrict__ part2,
                                                   float* __restrict__ out) {
    const size_t SEG = (size_t)BATCH * MPAD * COUT;
    int i = blockIdx.x * 256 + threadIdx.x;
    int c = i & (COUT - 1);
    int m = (i >> 9) & (MPAD - 1);
    int b = i >> 17;
    if (m >= 250) return;
    float s = part2[i] + part2[i + SEG] + part2[i + 2 * SEG] + part2[i + 3 * SEG];
    int box = m / 25, bin = m - box * 25;
    out[640 + ((size_t)(b * NBOX + box) * COUT + c) * 25 + bin] = s * 0.015625f;
}

extern "C" void kernel_launch(void* const* d_in, const int* in_sizes, int n_in,
                              void* d_out, int out_size, void* d_ws, size_t ws_size,
                              hipStream_t stream) {
    const float* c3     = (const float*)d_in[0];
    const float* c4     = (const float*)d_in[1];
    const float* boxes  = (const float*)d_in[2];
    const float* w_conv = (const float*)d_in[3];
    const float* b_conv = (const float*)d_in[4];
    const float* bng    = (const float*)d_in[5];
    const float* bnb    = (const float*)d_in[6];
    const float* bnm    = (const float*)d_in[7];
    const float* bnv    = (const float*)d_in[8];
    float* out = (float*)d_out;

    char* ws = (char*)d_ws;
    // fp8 layout (no aliasing needed):
    unsigned char* fusedT = (unsigned char*)ws;                 // 100663296 B
    unsigned char* P      = (unsigned char*)(ws + 100663296);   //  16777216 B
    float*         part2  = (float*)(ws + 117440512);           //  33554432 B
    unsigned char* w8     = (unsigned char*)(ws + 150994944);   //    786432 B
    float*         scale  = (float*)(ws + 151781376);           //      2048 B
    float*         shift  = (float*)(ws + 151783424);           //      2048 B
    unsigned char* attr   = (unsigned char*)(ws + 151785472);   //  33554432 B

    mega_pre<<<NB_TOT, 256, 0, stream>>>(c3, c4, boxes, w_conv, b_conv,
                                         bng, bnb, bnm, bnv,
                                         fusedT, P, w8, scale, shift, out);
    gemm_bn_relu<<<dim3(16, 2, 16), 512, 0, stream>>>(w8, fusedT, scale, shift, attr);
    pool_gemm<<<dim3(2, 16, 16), 256, 0, stream>>>(P, attr, part2);
    pool_reduce<<<(BATCH * MPAD * COUT) / 256, 256, 0, stream>>>(part2, out);
    (void)in_sizes; (void)n_in; (void)out_size; (void)ws_size;
}

// Round 9
// 376.868 us; speedup vs baseline: 1.0494x; 1.0069x over previous
//
#include <hip/hip_runtime.h>
#include <stdint.h>

#define FH 64
#define FW 64
#define CIN 1536
#define C3C 512
#define C4C 1024
#define COUT 512
#define BATCH 16
#define NPIX 4096
#define NBOX 10
#define MPAD 256   // 10 boxes * 25 bins = 250, padded
#define KT128 12   // CIN/128 K-tiles

// mega_pre flat-grid segments
#define NB_FU 12288              // build_fusedT: 12*64*16 (single-y blocks)
#define NB_P  4000               // build_P: 160*25
#define NB_W  768                // conv_w: 196608/256
#define NB_BN 2                  // prep_bn: 512/256
#define NB_CP 3                  // boxes->out copy: 640/256 rounded up
#define NB_TOT (NB_FU + NB_P + NB_W + NB_BN + NB_CP)

typedef float v4f __attribute__((ext_vector_type(4)));
typedef long  v2l __attribute__((ext_vector_type(2)));

#define GLOAD_LDS16(g, l) __builtin_amdgcn_global_load_lds( \
    (const __attribute__((address_space(1))) void*)(g),     \
    (__attribute__((address_space(3))) void*)(l), 16, 0, 0)

#define BARRIER() asm volatile("s_barrier" ::: "memory")

// pack 4 floats -> 4 fp8 e4m3 bytes in one u32 (byte k = f[k])
__device__ __forceinline__ uint32_t pack4_fp8(float a, float b, float c, float d) {
    int lo = __builtin_amdgcn_cvt_pk_fp8_f32(a, b, 0, false);
    int v  = __builtin_amdgcn_cvt_pk_fp8_f32(c, d, lo, true);
    return (uint32_t)v;
}
__device__ __forceinline__ unsigned char f32_to_fp8(float a) {
    return (unsigned char)(__builtin_amdgcn_cvt_pk_fp8_f32(a, a, 0, false) & 0xff);
}

// K-permutation within each 128-byte K-block (applied to w8/fusedT K=channels,
// and NOW ALSO to attr/P K=pixels):
// logical k7 stored at byte quad*32 + s*8 + b  (quad=(k7>>3)&3, s=k7>>5, b=k7&7).
// Makes each lane's MFMA operand pair {s,s+1} 16 contiguous bytes -> ds_read_b128.
// Applied identically to BOTH operands of each GEMM, so dot products are preserved.
// Word-level bijection: word w lands at word index
//   w'(w) = ((w>>1)&3)*8 + (w>>3)*2 + (w&1)
// 8-byte-group bijection: group g (k7>>3) lands at byte off (g&3)*32 + (g>>2)*8.

// ---------------- mega_pre: all input-only stages in ONE dispatch ----------
__global__ __launch_bounds__(256) void mega_pre(
        const float* __restrict__ c3, const float* __restrict__ c4,
        const float* __restrict__ boxes,
        const float* __restrict__ w_conv, const float* __restrict__ b_conv,
        const float* __restrict__ bng, const float* __restrict__ bnb,
        const float* __restrict__ bnm, const float* __restrict__ bnv,
        unsigned char* __restrict__ fusedT, unsigned char* __restrict__ P,
        unsigned char* __restrict__ w8,
        float* __restrict__ scale, float* __restrict__ shift,
        float* __restrict__ out) {
    __shared__ uint32_t lds[64 * 36];
    const int bid = blockIdx.x;
    const int t   = threadIdx.x;

    if (bid < NB_FU) {
        int ct = bid % 12;            // 0..11; <4 -> c3, else c4
        int rest = bid / 12;
        int y  = rest & 63;
        int b  = rest >> 6;
        int pg = t & 15;              // pixel quad: px 4pg..4pg+3
        int cq = t >> 4;              // 0..15; cquad = cq + 16r

        #pragma unroll
        for (int r = 0; r < 2; ++r) {
            int cquad = cq + 16 * r;
            float vv[4][4];           // [channel][pixel]
            if (ct < 4) {
                int ch = ct * 128 + 4 * cquad;
                const float* src = c3 + (((size_t)(b * C3C + ch) * FH + y) * FW) + 4 * pg;
                #pragma unroll
                for (int k = 0; k < 4; ++k) {
                    float4 f = *(const float4*)(src + (size_t)k * (FH * FW));
                    vv[k][0] = f.x; vv[k][1] = f.y; vv[k][2] = f.z; vv[k][3] = f.w;
                }
            } else {
                int ch = ct * 128 - 512 + 4 * cquad;
                int jy = y >> 1;
                int jyB = min(max(jy + ((y & 1) ? 1 : -1), 0), 31);
                const float* base = c4 + (size_t)(b * C4C + ch) * 1024;
                #pragma unroll
                for (int k = 0; k < 4; ++k) {
                    const float* pc = base + (size_t)k * 1024;
                    float2 f0 = *(const float2*)(pc + jy * 32 + 2 * pg);
                    float2 f1 = *(const float2*)(pc + jyB * 32 + 2 * pg);
                    float rbA = 0.75f * f0.x + 0.25f * f1.x;   // rb[2pg]
                    float rbB = 0.75f * f0.y + 0.25f * f1.y;   // rb[2pg+1]
                    float rbm = __shfl_up(rbB, 1, 16);          // rb[2pg-1]
                    float rbp = __shfl_down(rbA, 1, 16);        // rb[2pg+2]
                    if (pg == 0)  rbm = rbA;                    // km clamp
                    if (pg == 15) rbp = rbB;                    // kp clamp
                    vv[k][0] = 0.75f * rbA + 0.25f * rbm;
                    vv[k][1] = 0.75f * rbA + 0.25f * rbB;
                    vv[k][2] = 0.75f * rbB + 0.25f * rbA;
                    vv[k][3] = 0.75f * rbB + 0.25f * rbp;
                }
            }
            // permuted word index
            int wp = ((cquad >> 1) & 3) * 8 + (cquad >> 3) * 2 + (cquad & 1);
            #pragma unroll
            for (int i = 0; i < 4; ++i) {
                int px = 4 * pg + i;
                lds[px * 36 + 4 * ((wp >> 2) ^ ((px >> 1) & 7)) + (wp & 3)] =
                    pack4_fp8(vv[0][i], vv[1][i], vv[2][i], vv[3][i]);
            }
        }
        __syncthreads();
        // write: 64 px x 128 B; thread covers one 16-B permuted chunk
        int g = t & 7;
        #pragma unroll
        for (int rr2 = 0; rr2 < 2; ++rr2) {
            int px = (t >> 3) + 32 * rr2;
            uint4 w = *(const uint4*)(&lds[px * 36 + 4 * (g ^ ((px >> 1) & 7))]);
            *(uint4*)(fusedT + ((size_t)b * NPIX + y * FW + px) * CIN + ct * 128 + g * 16) = w;
        }
    } else if (bid < NB_FU + NB_P) {
        // ---- build pooling matrix P[b][m][pix] fp8 (x64), pixel k-permuted ----
        int id  = bid - NB_FU;
        int br  = id % 160;
        int m25 = id / 160;
        int b   = br / NBOX;
        int m   = (br % NBOX) * 25 + m25;
        int p   = m25 / 5, q = m25 % 5;
        int y   = t >> 2;
        int x0  = (t & 3) * 16;
        const float* bx = boxes + (size_t)br * 4;
        int x1 = min(max((int)floorf(bx[0] * 0.125f), 0), 63);
        int y1 = min(max((int)floorf(bx[1] * 0.125f), 0), 63);
        int x2 = min(max((int)ceilf (bx[2] * 0.125f), 0), 63);
        int y2 = min(max((int)ceilf (bx[3] * 0.125f), 0), 63);
        if (x2 <= x1) x2 = min(x1 + 1, 64);
        if (y2 <= y1) y2 = min(y1 + 1, 64);
        int Lx = x2 - x1, Ly = y2 - y1;
        int sx = x1 + (q * Lx) / 5;
        int ex = x1 + ((q + 1) * Lx + 4) / 5;
        int sy = y1 + (p * Ly) / 5;
        int ey = y1 + ((p + 1) * Ly + 4) / 5;
        float wyv  = (y >= sy && y < ey) ? 1.0f / (float)(ey - sy) : 0.0f;
        float pval = 64.0f * wyv / (float)(ex - sx);
        float v[16];
        #pragma unroll
        for (int i = 0; i < 16; ++i) {
            int xi = x0 + i;
            v[i] = (xi >= sx && xi < ex) ? pval : 0.0f;
        }
        uint4 w;
        w.x = pack4_fp8(v[0],  v[1],  v[2],  v[3]);
        w.y = pack4_fp8(v[4],  v[5],  v[6],  v[7]);
        w.z = pack4_fp8(v[8],  v[9],  v[10], v[11]);
        w.w = pack4_fp8(v[12], v[13], v[14], v[15]);
        // pixel block = (y>>1)*128; 8-byte groups g0 (bytes 0-7) and g0+1 (8-15)
        unsigned char* dst = P + ((size_t)b * MPAD + m) * NPIX + (y >> 1) * 128;
        int g0 = 8 * (y & 1) + 2 * (t & 3);
        int g1 = g0 + 1;
        *(uint2*)(dst + (g0 & 3) * 32 + (g0 >> 2) * 8) = make_uint2(w.x, w.y);
        *(uint2*)(dst + (g1 & 3) * 32 + (g1 >> 2) * 8) = make_uint2(w.z, w.w);
    } else if (bid < NB_FU + NB_P + NB_W) {
        // ---- W f32 -> fp8 (x16), k-permuted layout ----
        int i = (bid - NB_FU - NB_P) * 256 + t;
        if (i < COUT * CIN / 4) {
            float4 f = *(const float4*)(w_conv + i * 4);
            uint32_t v = pack4_fp8(f.x * 16.0f, f.y * 16.0f, f.z * 16.0f, f.w * 16.0f);
            int c0 = (i * 4) % CIN;
            int o  = (i * 4) / CIN;
            int k7 = c0 & 127;
            int pos = ((k7 >> 3) & 3) * 32 + (k7 >> 5) * 8 + (k7 & 7);
            *(uint32_t*)(w8 + (size_t)o * CIN + (c0 & ~127) + pos) = v;
        }
    } else if (bid < NB_FU + NB_P + NB_W + NB_BN) {
        // ---- BN constant folding ----
        int o = (bid - NB_FU - NB_P - NB_W) * 256 + t;
        if (o < COUT) {
            float inv = bng[o] / sqrtf(bnv[o] + 1e-5f);
            scale[o] = inv * 0.0625f;             // /16: W quantized as W*16
            shift[o] = bnb[o] + inv * (b_conv[o] - bnm[o]);
        }
    } else {
        // ---- boxes -> out[0:640] copy (replaces hipMemcpyAsync) ----
        int i = (bid - NB_FU - NB_P - NB_W - NB_BN) * 256 + t;
        if (i < 640) out[i] = boxes[i];
    }
}

// ---------------- fp8 GEMM + BN + ReLU, 256x256 tile, BK=128, 2-phase ------
// k-permuted operands -> each fragment pair is one conflict-free
// ds_read_b128; counted vmcnt, raw s_barrier, setprio around MFMA.
// Epilogue stores attr with PIXEL k-permutation (pool's K dim) so the
// pool GEMM also gets conflict-free b128 reads.
__global__ __launch_bounds__(512, 2) void gemm_bn_relu(
        const unsigned char* __restrict__ w8,
        const unsigned char* __restrict__ fusedT,
        const float* __restrict__ scale, const float* __restrict__ shift,
        unsigned char* __restrict__ attr) {
    __shared__ __align__(16) unsigned char lds_a[2][32768];
    __shared__ __align__(16) unsigned char lds_b[2][32768];
    const int t  = threadIdx.x;
    const int n0 = blockIdx.x * 256;   // pixel tile
    const int o0 = blockIdx.y * 256;   // out-channel tile
    const int b  = blockIdx.z;
    const int wave = t >> 6, lane = t & 63;
    const int wm = wave & 1, wn = wave >> 1;   // 2 x 4 wave grid
    const int quad = lane >> 4, l16 = lane & 15;
    const int cp0 = (((quad << 1) ^ (l16 & 7)) << 4);
    const int cp1 = cp0 ^ 16;
    const unsigned char* fb = fusedT + (size_t)b * NPIX * CIN;

    // ---- staging: 512 threads cover one 64row x 128B unit ----
    const int rr = t >> 3;                        // row within unit (0..63)
    const int cg = (t & 7) ^ (rr & 7);            // inverse-swizzled src chunk
    const unsigned char* gA = w8 + (size_t)(o0 + rr) * CIN + cg * 16;
    const unsigned char* gB = fb + (size_t)(n0 + rr) * CIN + cg * 16;

#define SA(u, kt, d) GLOAD_LDS16(gA + (size_t)(u) * (64 * CIN) + (kt) * 128, \
                                 &lds_a[d][(u) * 8192 + t * 16])
#define SB(u, kt, d) GLOAD_LDS16(gB + (size_t)(u) * (64 * CIN) + (kt) * 128, \
                                 &lds_b[d][(u) * 8192 + t * 16])
#define RAV(d, ph, i, cp) (*(const v2l*)(&lds_a[d][((wm * 128 + (ph) * 64 + (i) * 16 + l16) << 7) + (cp)]))
#define RBV(d, j, cp)     (*(const v2l*)(&lds_b[d][((wn * 64 + (j) * 16 + l16) << 7) + (cp)]))

    v4f acc[8][4];   // [ph*4+i][j]
    #pragma unroll
    for (int i = 0; i < 8; ++i)
        #pragma unroll
        for (int j = 0; j < 4; ++j) acc[i][j] = (v4f)0.0f;

    // ---- prologue: tile0 full (8 units) + S1(tile1) (6 units) ----
    SA(0, 0, 0); SA(1, 0, 0); SA(2, 0, 0); SA(3, 0, 0);
    SB(0, 0, 0); SB(1, 0, 0); SB(2, 0, 0); SB(3, 0, 0);
    SA(0, 1, 1); SA(2, 1, 1); SB(0, 1, 1); SB(1, 1, 1); SB(2, 1, 1); SB(3, 1, 1);
    asm volatile("s_waitcnt vmcnt(6)" ::: "memory");
    BARRIER();

    v2l ah0[4], ah1[4], bh0[4], bh1[4];

    for (int kt = 0; kt < KT128; ++kt) {
        const int cur = kt & 1, nxt = cur ^ 1;

        // ---- phase 1: A rows wm*128..+64 x all B ----
        #pragma unroll
        for (int i = 0; i < 4; ++i) { ah0[i] = RAV(cur, 0, i, cp0); ah1[i] = RAV(cur, 0, i, cp1); }
        #pragma unroll
        for (int j = 0; j < 4; ++j) { bh0[j] = RBV(cur, j, cp0); bh1[j] = RBV(cur, j, cp1); }
        if (kt > 0 && kt + 1 < KT128) {
            SA(0, kt + 1, nxt); SA(2, kt + 1, nxt);
            SB(0, kt + 1, nxt); SB(1, kt + 1, nxt);
            SB(2, kt + 1, nxt); SB(3, kt + 1, nxt);
        }
        __builtin_amdgcn_s_setprio(1);
        #pragma unroll
        for (int s = 0; s < 2; ++s)
            #pragma unroll
            for (int i = 0; i < 4; ++i)
                #pragma unroll
                for (int j = 0; j < 4; ++j)
                    acc[i][j] = __builtin_amdgcn_mfma_f32_16x16x32_fp8_fp8(ah0[i][s], bh0[j][s], acc[i][j], 0, 0, 0);
        #pragma unroll
        for (int s = 0; s < 2; ++s)
            #pragma unroll
            for (int i = 0; i < 4; ++i)
                #pragma unroll
                for (int j = 0; j < 4; ++j)
                    acc[i][j] = __builtin_amdgcn_mfma_f32_16x16x32_fp8_fp8(ah1[i][s], bh1[j][s], acc[i][j], 0, 0, 0);
        __builtin_amdgcn_s_setprio(0);
        if (kt + 1 < KT128) { asm volatile("s_waitcnt vmcnt(6)" ::: "memory"); }
        else               { asm volatile("s_waitcnt vmcnt(0)" ::: "memory"); }
        BARRIER();

        // ---- phase 2: A rows wm*128+64..+128 (B frags reused) ----
        #pragma unroll
        for (int i = 0; i < 4; ++i) { ah0[i] = RAV(cur, 1, i, cp0); ah1[i] = RAV(cur, 1, i, cp1); }
        if (kt + 1 < KT128) { SA(1, kt + 1, nxt); SA(3, kt + 1, nxt); }
        __builtin_amdgcn_s_setprio(1);
        #pragma unroll
        for (int s = 0; s < 2; ++s)
            #pragma unroll
            for (int i = 0; i < 4; ++i)
                #pragma unroll
                for (int j = 0; j < 4; ++j)
                    acc[4 + i][j] = __builtin_amdgcn_mfma_f32_16x16x32_fp8_fp8(ah0[i][s], bh0[j][s], acc[4 + i][j], 0, 0, 0);
        #pragma unroll
        for (int s = 0; s < 2; ++s)
            #pragma unroll
            for (int i = 0; i < 4; ++i)
                #pragma unroll
                for (int j = 0; j < 4; ++j)
                    acc[4 + i][j] = __builtin_amdgcn_mfma_f32_16x16x32_fp8_fp8(ah1[i][s], bh1[j][s], acc[4 + i][j], 0, 0, 0);
        __builtin_amdgcn_s_setprio(0);
        if (kt + 1 < KT128) { asm volatile("s_waitcnt vmcnt(2)" ::: "memory"); }
        BARRIER();
    }

    // ---- epilogue: BN + ReLU + fp8 channel-major store, pixel k-permuted ----
    unsigned char* ab = attr + (size_t)b * COUT * NPIX;
    // permuted pixel index per j (pixel K-permutation for the pool GEMM):
    // k7 = (wn&1)*64 + j*16 + l16 -> pos = ((k7>>3)&3)*32 + (k7>>5)*8 + (k7&7)
    int nn[4];
    #pragma unroll
    for (int j = 0; j < 4; ++j)
        nn[j] = n0 + (wn >> 1) * 128 + ((2 * j + (l16 >> 3)) & 3) * 32
              + (2 * (wn & 1) + (j >> 1)) * 8 + (l16 & 7);
    #pragma unroll
    for (int a = 0; a < 8; ++a) {
        int obase = o0 + wm * 128 + (a >> 2) * 64 + (a & 3) * 16 + quad * 4;
        #pragma unroll
        for (int r = 0; r < 4; ++r) {
            int oo = obase + r;
            float sc = scale[oo], sh = shift[oo];
            #pragma unroll
            for (int j = 0; j < 4; ++j) {
                float v = fmaxf(acc[a][j][r] * sc + sh, 0.0f);
                ab[(size_t)oo * NPIX + nn[j]] = f32_to_fp8(v);
            }
        }
    }
#undef SA
#undef SB
#undef RAV
#undef RBV
}

// ---------------- fp8 pool GEMM, K-split x4, BK=128 b128 pipeline ----------
// R8 upgrade: attr/P are pixel-k-permuted -> conflict-free ds_read_b128
// (same cp0/cp1 machinery as the main GEMM). Double-buffered LDS (64 KB ->
// 2 blocks/CU for cross-block overlap), lookahead-1 staging issued under
// the 64-MFMA cluster (R4-proven hazard pattern: stage only into nxt).
__global__ __launch_bounds__(256) void pool_gemm(
        const unsigned char* __restrict__ P,
        const unsigned char* __restrict__ attr,
        float* __restrict__ part2) {
    __shared__ __align__(16) unsigned char lds_a[2][16384];
    __shared__ __align__(16) unsigned char lds_b[2][16384];
    int t  = threadIdx.x;
    int m0 = blockIdx.x * 128;
    int c0 = (blockIdx.y & 3) * 128;
    int seg = blockIdx.y >> 2;
    int b  = blockIdx.z;
    int wave = t >> 6, lane = t & 63;
    int wm = wave & 1, wn = wave >> 1;          // 2 x 2 wave grid
    int quad = lane >> 4, l16 = lane & 15;
    const int cp0 = (((quad << 1) ^ (l16 & 7)) << 4);
    const int cp1 = cp0 ^ 16;
    const unsigned char* Pb = P + (size_t)b * MPAD * NPIX + seg * 1024;
    const unsigned char* ab = attr + (size_t)b * COUT * NPIX + seg * 1024;

    // staging: 256 threads cover one 32row x 128B unit (4 units per operand)
    int rr = t >> 3;                            // row within unit (0..31)
    int cg = (t & 7) ^ (rr & 7);                // inverse-swizzled src chunk
    const unsigned char* gA = Pb + (size_t)(m0 + rr) * NPIX + cg * 16;
    const unsigned char* gB = ab + (size_t)(c0 + rr) * NPIX + cg * 16;

#define SPA(u, st, d) GLOAD_LDS16(gA + (size_t)(u) * (32 * NPIX) + (st) * 128, \
                                  &lds_a[d][(u) * 4096 + t * 16])
#define SPB(u, st, d) GLOAD_LDS16(gB + (size_t)(u) * (32 * NPIX) + (st) * 128, \
                                  &lds_b[d][(u) * 4096 + t * 16])
#define PRA(d, i, cp) (*(const v2l*)(&lds_a[d][((wm * 64 + (i) * 16 + l16) << 7) + (cp)]))
#define PRB(d, j, cp) (*(const v2l*)(&lds_b[d][((wn * 64 + (j) * 16 + l16) << 7) + (cp)]))

    v4f acc[4][4];
    #pragma unroll
    for (int i = 0; i < 4; ++i)
        #pragma unroll
        for (int j = 0; j < 4; ++j) acc[i][j] = (v4f)0.0f;

    // prologue: step 0 -> buf0
    SPA(0, 0, 0); SPA(1, 0, 0); SPA(2, 0, 0); SPA(3, 0, 0);
    SPB(0, 0, 0); SPB(1, 0, 0); SPB(2, 0, 0); SPB(3, 0, 0);
    asm volatile("s_waitcnt vmcnt(0)" ::: "memory");
    BARRIER();

    for (int k = 0; k < 8; ++k) {
        const int cur = k & 1, nxt = cur ^ 1;
        v2l a0[4], a1[4], b0[4], b1[4];
        #pragma unroll
        for (int i = 0; i < 4; ++i) { a0[i] = PRA(cur, i, cp0); a1[i] = PRA(cur, i, cp1); }
        #pragma unroll
        for (int j = 0; j < 4; ++j) { b0[j] = PRB(cur, j, cp0); b1[j] = PRB(cur, j, cp1); }
        if (k + 1 < 8) {
            SPA(0, k + 1, nxt); SPA(1, k + 1, nxt); SPA(2, k + 1, nxt); SPA(3, k + 1, nxt);
            SPB(0, k + 1, nxt); SPB(1, k + 1, nxt); SPB(2, k + 1, nxt); SPB(3, k + 1, nxt);
        }
        __builtin_amdgcn_s_setprio(1);
        #pragma unroll
        for (int s = 0; s < 2; ++s)
            #pragma unroll
            for (int i = 0; i < 4; ++i)
                #pragma unroll
                for (int j = 0; j < 4; ++j)
                    acc[i][j] = __builtin_amdgcn_mfma_f32_16x16x32_fp8_fp8(a0[i][s], b0[j][s], acc[i][j], 0, 0, 0);
        #pragma unroll
        for (int s = 0; s < 2; ++s)
            #pragma unroll
            for (int i = 0; i < 4; ++i)
                #pragma unroll
                for (int j = 0; j < 4; ++j)
                    acc[i][j] = __builtin_amdgcn_mfma_f32_16x16x32_fp8_fp8(a1[i][s], b1[j][s], acc[i][j], 0, 0, 0);
        __builtin_amdgcn_s_setprio(0);
        asm volatile("s_waitcnt vmcnt(0)" ::: "memory");
        BARRIER();
    }

    float* pp = part2 + (((size_t)seg * BATCH + b) * MPAD) * COUT;
    #pragma unroll
    for (int i = 0; i < 4; ++i) {
        #pragma unroll
        for (int r = 0; r < 4; ++r) {
            int mrow = m0 + wm * 64 + i * 16 + quad * 4 + r;
            #pragma unroll
            for (int j = 0; j < 4; ++j) {
                int c = c0 + wn * 64 + j * 16 + l16;
                pp[(size_t)mrow * COUT + c] = acc[i][j][r];
            }
        }
    }
#undef SPA
#undef SPB
#undef PRA
#undef PRB
}

// ---------------- reduce 4 segs (/64 for P scaling), transpose to out ------
__global__ __launch_bounds__(256) void pool_reduce(const float* __restrict__ part2,
                                                   float* __restrict__ out) {
    const size_t SEG = (size_t)BATCH * MPAD * COUT;
    int i = blockIdx.x * 256 + threadIdx.x;
    int c = i & (COUT - 1);
    int m = (i >> 9) & (MPAD - 1);
    int b = i >> 17;
    if (m >= 250) return;
    float s = part2[i] + part2[i + SEG] + part2[i + 2 * SEG] + part2[i + 3 * SEG];
    int box = m / 25, bin = m - box * 25;
    out[640 + ((size_t)(b * NBOX + box) * COUT + c) * 25 + bin] = s * 0.015625f;
}

extern "C" void kernel_launch(void* const* d_in, const int* in_sizes, int n_in,
                              void* d_out, int out_size, void* d_ws, size_t ws_size,
                              hipStream_t stream) {
    const float* c3     = (const float*)d_in[0];
    const float* c4     = (const float*)d_in[1];
    const float* boxes  = (const float*)d_in[2];
    const float* w_conv = (const float*)d_in[3];
    const float* b_conv = (const float*)d_in[4];
    const float* bng    = (const float*)d_in[5];
    const float* bnb    = (const float*)d_in[6];
    const float* bnm    = (const float*)d_in[7];
    const float* bnv    = (const float*)d_in[8];
    float* out = (float*)d_out;

    char* ws = (char*)d_ws;
    // fp8 layout (no aliasing needed):
    unsigned char* fusedT = (unsigned char*)ws;                 // 100663296 B
    unsigned char* P      = (unsigned char*)(ws + 100663296);   //  16777216 B
    float*         part2  = (float*)(ws + 117440512);           //  33554432 B
    unsigned char* w8     = (unsigned char*)(ws + 150994944);   //    786432 B
    float*         scale  = (float*)(ws + 151781376);           //      2048 B
    float*         shift  = (float*)(ws + 151783424);           //      2048 B
    unsigned char* attr   = (unsigned char*)(ws + 151785472);   //  33554432 B

    mega_pre<<<NB_TOT, 256, 0, stream>>>(c3, c4, boxes, w_conv, b_conv,
                                         bng, bnb, bnm, bnv,
                                         fusedT, P, w8, scale, shift, out);
    gemm_bn_relu<<<dim3(16, 2, 16), 512, 0, stream>>>(w8, fusedT, scale, shift, attr);
    pool_gemm<<<dim3(2, 16, 16), 256, 0, stream>>>(P, attr, part2);
    pool_reduce<<<(BATCH * MPAD * COUT) / 256, 256, 0, stream>>>(part2, out);
    (void)in_sizes; (void)n_in; (void)out_size; (void)ws_size;
}